// Round 2
// baseline (3384.188 us; speedup 1.0000x reference)
//
#include <hip/hip_runtime.h>
#include <math.h>

#define LL 1024
#define BB 4
#define HH 8
#define EE 64
#define CC (HH*EE)  // 512

// ---------------- kernel 1: Hilbert circular-conv kernel table ----------------
// gi[d] = (2/L)*cot(pi*d/L) for odd d, else 0.  (even-L discrete Hilbert kernel)
__global__ void k_gi(float* gi) {
    int d = blockIdx.x * blockDim.x + threadIdx.x;
    if (d >= LL) return;
    float v = 0.f;
    if (d & 1) {
        float a = 3.14159265358979323846f * (float)d / (float)LL;
        v = (2.0f / (float)LL) * (cosf(a) / sinf(a));
    }
    gi[d] = v;
}

// ---------------- kernel 2: hurst->psi cumsum, tau_t ----------------
__global__ __launch_bounds__(1024) void k_scan(const float* __restrict__ hurst,
                                               const float* __restrict__ tau,
                                               float* __restrict__ psi,
                                               float* __restrict__ taut) {
    __shared__ float s[LL];
    int bh = blockIdx.x;
    int b = bh / HH, h = bh % HH;
    int l = threadIdx.x;
    float hu = hurst[((size_t)b * LL + l) * HH + h];
    float ht = 1.f / (1.f + expf(-hu)) * 0.99f + 0.01f;
    s[l] = expf(2.0f * ht);
    __syncthreads();
    for (int off = 1; off < LL; off <<= 1) {
        float t = (l >= off) ? s[l - off] : 0.f;
        __syncthreads();
        s[l] += t;
        __syncthreads();
    }
    psi[((size_t)b * HH + h) * LL + l] = s[l];
    float tv = tau[((size_t)b * LL + l) * HH + h];
    taut[((size_t)b * HH + h) * LL + l] = 1.f / (1.f + expf(-tv)) * 0.9f + 0.1f;
}

// ---------------- kernel 3: per-batch Hilbert circular conv over SCRAMBLED view ----
// Reference bug (faithful): x = transpose(q,(0,2,1,3)).reshape(B,L,H*E)
// => x[b,i,c] = q[b, l, h, e] with h=i>>7, l=((i&127)<<3)|(c>>6), e=c&63.
// im[i,c] = sum_m gi[(i-m) mod L] * x[b,m,c]
__global__ __launch_bounds__(256) void k_hilb(const float* __restrict__ q,
                                              const float* __restrict__ gi,
                                              float* __restrict__ im, int b) {
    __shared__ float gs[LL];
    int t = threadIdx.x;
    for (int i = t; i < LL; i += 256) gs[i] = gi[i];
    __syncthreads();
    int cy = blockIdx.y;            // c>>6, constant per block
    int e  = t & 63;                // c&63
    int i  = blockIdx.x * 4 + (t >> 6);
    const float* qb = q + (size_t)b * LL * CC;
    float acc = 0.f;
    #pragma unroll 4
    for (int m = 0; m < LL; m++) {
        int l = ((m & 127) << 3) | cy;
        int h = m >> 7;
        float xv = qb[((size_t)l * HH + h) * EE + e];
        acc += gs[(i - m) & (LL - 1)] * xv;
    }
    im[(size_t)i * CC + cy * 64 + e] = acc;
}

// ---------------- kernel 4: theta[b,i] over scrambled view ----------------
__global__ __launch_bounds__(256) void k_theta(const float* __restrict__ q,
                                               const float* __restrict__ im,
                                               float* __restrict__ theta, int b) {
    __shared__ float ss[256], sc[256];
    int i = blockIdx.x, t = threadIdx.x;
    const float* qb = q + (size_t)b * LL * CC;
    int h = i >> 7;
    float ssum = 0.f, csum = 0.f;
    for (int c = t; c < CC; c += 256) {
        int l = ((i & 127) << 3) | (c >> 6);
        int e = c & 63;
        float re = qb[((size_t)l * HH + h) * EE + e];
        float iv = im[(size_t)i * CC + c];
        float r = sqrtf(re * re + iv * iv);
        if (r > 0.f) { ssum += iv / r; csum += re / r; }
        else { csum += 1.f; }  // atan2(0,0)=0 -> sin=0, cos=1
    }
    ss[t] = ssum; sc[t] = csum;
    __syncthreads();
    for (int off = 128; off > 0; off >>= 1) {
        if (t < off) { ss[t] += ss[t + off]; sc[t] += sc[t + off]; }
        __syncthreads();
    }
    if (t == 0) theta[(size_t)b * LL + i] = atan2f(ss[0], sc[0]);
}

// ---------------- kernel 5: fused attention ----------------
__global__ __launch_bounds__(256) void k_attn(const float* __restrict__ q,
                                              const float* __restrict__ k,
                                              const float* __restrict__ v,
                                              const float* __restrict__ psi,
                                              const float* __restrict__ taut,
                                              const float* __restrict__ theta,
                                              float* __restrict__ out) {
    __shared__ float qs[EE];
    __shared__ float attn[LL];
    __shared__ float prg[LL];
    __shared__ float red[256];
    __shared__ float vred[4][EE];

    int idx = blockIdx.x;                  // ((b*H + h)*L + l)
    int l = idx % LL;
    int bh = idx / LL;
    int h = bh % HH, b = bh / HH;
    int t = threadIdx.x;

    if (t < EE) qs[t] = q[(((size_t)b * LL + l) * HH + h) * EE + t];
    __syncthreads();

    const float* psibh = psi + ((size_t)b * HH + h) * LL;
    const float* thb = theta + (size_t)b * LL;
    float psi_l = psibh[l];
    float tau_l = taut[((size_t)b * HH + h) * LL + l];
    float th_l = thb[l];
    float inv2t2 = 1.f / (2.f * tau_l * tau_l);

    float mloc = -INFINITY, spr = 0.f, sprg = 0.f;
    const float4* q4 = (const float4*)qs;
    for (int s = t; s < LL; s += 256) {
        const float* kp = k + (((size_t)b * LL + s) * HH + h) * EE;
        const float4* kp4 = (const float4*)kp;
        float dot = 0.f;
        #pragma unroll
        for (int e = 0; e < EE / 4; e++) {
            float4 kv = kp4[e], qv = q4[e];
            dot += qv.x * kv.x + qv.y * kv.y + qv.z * kv.z + qv.w * kv.w;
        }
        float a = 0.125f * dot;
        attn[s] = a;
        mloc = fmaxf(mloc, a);
        float d = psi_l - psibh[s];
        float pr = expf(-0.5f * d * d);
        float dphi = sinf(0.5f * (th_l - thb[s]));
        float g = expf(-dphi * dphi * inv2t2);
        float pg = pr * g;
        prg[s] = pg;
        spr += pr;
        sprg += pg;
    }

    red[t] = mloc; __syncthreads();
    for (int off = 128; off > 0; off >>= 1) {
        if (t < off) red[t] = fmaxf(red[t], red[t + off]);
        __syncthreads();
    }
    float ma = red[0]; __syncthreads();

    red[t] = spr; __syncthreads();
    for (int off = 128; off > 0; off >>= 1) {
        if (t < off) red[t] += red[t + off];
        __syncthreads();
    }
    float sprT = red[0]; __syncthreads();

    red[t] = sprg; __syncthreads();
    for (int off = 128; off > 0; off >>= 1) {
        if (t < off) red[t] += red[t + off];
        __syncthreads();
    }
    float sprgT = red[0]; __syncthreads();

    float se = 0.f;
    for (int s = t; s < LL; s += 256) {
        float eA = expf(attn[s] - ma);
        attn[s] = eA;
        se += eA;
    }
    red[t] = se; __syncthreads();
    for (int off = 128; off > 0; off >>= 1) {
        if (t < off) red[t] += red[t + off];
        __syncthreads();
    }
    float seT = red[0]; __syncthreads();

    float cs = 0.9f / seT;
    float cp = 0.1f / (sprgT + 1e-6f * (sprT + 1e-6f));

    int e = t & 63, g = t >> 6;
    float acc = 0.f;
    for (int s = g; s < LL; s += 4) {
        float w = cs * attn[s] + cp * prg[s];
        acc += w * v[(((size_t)b * LL + s) * HH + h) * EE + e];
    }
    vred[g][e] = acc;
    __syncthreads();
    if (g == 0) {
        float r = vred[0][e] + vred[1][e] + vred[2][e] + vred[3][e];
        out[(((size_t)b * LL + l) * HH + h) * EE + e] = r;
    }
}

extern "C" void kernel_launch(void* const* d_in, const int* in_sizes, int n_in,
                              void* d_out, int out_size, void* d_ws, size_t ws_size,
                              hipStream_t stream) {
    const float* q = (const float*)d_in[0];
    const float* k = (const float*)d_in[1];
    const float* v = (const float*)d_in[2];
    // d_in[3] = sigma (unused by the reference)
    const float* hurst = (const float*)d_in[4];
    const float* tau = (const float*)d_in[5];
    float* out = (float*)d_out;

    float* ws = (float*)d_ws;
    float* gi    = ws;                       // 1024
    float* psi   = gi + LL;                  // B*H*L = 32768
    float* taut  = psi + (size_t)BB * HH * LL;   // 32768
    float* theta = taut + (size_t)BB * HH * LL;  // B*L = 4096
    float* im    = theta + (size_t)BB * LL;      // L*C = 524288 (one batch, reused)

    k_gi<<<1, LL, 0, stream>>>(gi);
    k_scan<<<BB * HH, LL, 0, stream>>>(hurst, tau, psi, taut);
    for (int b = 0; b < BB; b++) {
        dim3 gB(LL / 4, CC / 64);
        k_hilb<<<gB, 256, 0, stream>>>(q, gi, im, b);
        k_theta<<<LL, 256, 0, stream>>>(q, im, theta, b);
    }
    k_attn<<<BB * HH * LL, 256, 0, stream>>>(q, k, v, psi, taut, theta, out);
}

// Round 3
// 694.531 us; speedup vs baseline: 4.8726x; 4.8726x over previous
//
#include <hip/hip_runtime.h>
#include <math.h>

#define LL 1024
#define BB 4
#define HH 8
#define EE 64
#define CC (HH*EE)  // 512

#define QT 32       // query rows per block
#define ST 64       // key/value tile
#define NT (LL/ST)  // 16 tiles

// ---------------- kernel 1: Hilbert circular-conv kernel table ----------------
// gi[d] = (2/L)*cot(pi*d/L) for odd d, else 0.
__global__ void k_gi(float* gi) {
    int d = blockIdx.x * blockDim.x + threadIdx.x;
    if (d >= LL) return;
    float v = 0.f;
    if (d & 1) {
        float a = 3.14159265358979323846f * (float)d / (float)LL;
        v = (2.0f / (float)LL) * (cosf(a) / sinf(a));
    }
    gi[d] = v;
}

// ---------------- kernel 2: hurst->psi cumsum, tau_t ----------------
__global__ __launch_bounds__(1024) void k_scan(const float* __restrict__ hurst,
                                               const float* __restrict__ tau,
                                               float* __restrict__ psi,
                                               float* __restrict__ taut) {
    __shared__ float s[LL];
    int bh = blockIdx.x;
    int b = bh / HH, h = bh % HH;
    int l = threadIdx.x;
    float hu = hurst[((size_t)b * LL + l) * HH + h];
    float ht = 1.f / (1.f + expf(-hu)) * 0.99f + 0.01f;
    s[l] = expf(2.0f * ht);
    __syncthreads();
    for (int off = 1; off < LL; off <<= 1) {
        float t = (l >= off) ? s[l - off] : 0.f;
        __syncthreads();
        s[l] += t;
        __syncthreads();
    }
    psi[((size_t)b * HH + h) * LL + l] = s[l];
    float tv = tau[((size_t)b * LL + l) * HH + h];
    taut[((size_t)b * HH + h) * LL + l] = 1.f / (1.f + expf(-tv)) * 0.9f + 0.1f;
}

// ---------------- kernel 3: Hilbert circular conv over SCRAMBLED view ----------
// x[b,i,c] = q[b, l, h, e] with h=i>>7, l=((i&127)<<3)|(c>>6), e=c&63.
// im[i,c] = sum_m gi[(i-m) mod L] * x[b,m,c]
// Block: 16 i-rows (4 per thread-row), 64 e lanes, fixed cy = c>>6.
__global__ __launch_bounds__(256) void k_hilb(const float* __restrict__ q,
                                              const float* __restrict__ gi,
                                              float* __restrict__ im, int b) {
    __shared__ float T[2047];   // T[u] = gi[(1023-u) & 1023]
    int t = threadIdx.x;
    for (int x = t; x < 2047; x += 256) T[x] = gi[(1023 - x) & 1023];
    __syncthreads();
    int cy = blockIdx.y;          // c>>6
    int e  = t & 63;              // c&63
    int tr = t >> 6;              // 0..3
    int ibase = blockIdx.x * 16 + tr * 4;
    const float* qb = q + (size_t)b * LL * CC;
    int baseoff = (cy << 9) + e;  // cy*512 + e
    float a0 = 0.f, a1 = 0.f, a2 = 0.f, a3 = 0.f;
    int ub0 = 1023 - ibase;
    #pragma unroll 4
    for (int m = 0; m < LL; ++m) {
        int off = ((m & 127) << 12) + ((m >> 7) << 6) + baseoff;
        float xv = qb[off];
        int u = m + ub0;
        a0 += T[u]     * xv;
        a1 += T[u - 1] * xv;
        a2 += T[u - 2] * xv;
        a3 += T[u - 3] * xv;
    }
    int c = (cy << 6) + e;
    im[(size_t)(ibase + 0) * CC + c] = a0;
    im[(size_t)(ibase + 1) * CC + c] = a1;
    im[(size_t)(ibase + 2) * CC + c] = a2;
    im[(size_t)(ibase + 3) * CC + c] = a3;
}

// ---------------- kernel 4: theta[b,i] over scrambled view ----------------
__global__ __launch_bounds__(256) void k_theta(const float* __restrict__ q,
                                               const float* __restrict__ im,
                                               float* __restrict__ theta, int b) {
    __shared__ float ss[256], sc_[256];
    int i = blockIdx.x, t = threadIdx.x;
    const float* qb = q + (size_t)b * LL * CC;
    int h = i >> 7;
    float ssum = 0.f, csum = 0.f;
    for (int c = t; c < CC; c += 256) {
        int l = ((i & 127) << 3) | (c >> 6);
        int e = c & 63;
        float re = qb[((size_t)l * HH + h) * EE + e];
        float iv = im[(size_t)i * CC + c];
        float r = sqrtf(re * re + iv * iv);
        if (r > 0.f) { ssum += iv / r; csum += re / r; }
        else { csum += 1.f; }
    }
    ss[t] = ssum; sc_[t] = csum;
    __syncthreads();
    for (int off = 128; off > 0; off >>= 1) {
        if (t < off) { ss[t] += ss[t + off]; sc_[t] += sc_[t + off]; }
        __syncthreads();
    }
    if (t == 0) theta[(size_t)b * LL + i] = atan2f(ss[0], sc_[0]);
}

// ---------------- kernel 5: tiled flash-style fused attention ----------------
// grid: BB*HH*(LL/QT) blocks of 256 threads. Block handles QT query rows.
__global__ __launch_bounds__(256) void k_attn(const float* __restrict__ q,
                                              const float* __restrict__ k,
                                              const float* __restrict__ v,
                                              const float* __restrict__ psi,
                                              const float* __restrict__ taut,
                                              const float* __restrict__ theta,
                                              float* __restrict__ out) {
    __shared__ float kT[EE][ST + 4];    // k transposed: [e][s]
    __shared__ float vs[ST][EE];        // v natural:    [s][e]
    __shared__ float qT[EE][QT + 4];    // q transposed: [e][r]
    __shared__ float sc[QT][ST + 4];    // scores, then p=exp(a-m)
    __shared__ float pg[QT][ST + 4];    // prior*gate
    __shared__ float psi_s[ST], th_s[ST];
    __shared__ float psi_q[QT], th_q[QT], i2t_q[QT];

    int t = threadIdx.x;
    int blk = blockIdx.x;
    int qt = blk & (LL / QT - 1);
    int bh = blk >> 5;                  // LL/QT = 32
    int h = bh & (HH - 1), b = bh >> 3;
    int l0 = qt * QT;

    const float* kb = k + (size_t)b * LL * CC + (size_t)h * EE;
    const float* vb = v + (size_t)b * LL * CC + (size_t)h * EE;
    const float* psib = psi + (size_t)bh * LL;
    const float* thb = theta + (size_t)b * LL;

    // stage qT + per-row params
    for (int x = t; x < QT * EE; x += 256) {
        int e = x & 63, r = x >> 6;
        qT[e][r] = q[(size_t)b * LL * CC + (size_t)(l0 + r) * CC + (size_t)h * EE + e];
    }
    if (t < QT) {
        psi_q[t] = psib[l0 + t];
        th_q[t] = thb[l0 + t];
        float ta = taut[(size_t)bh * LL + l0 + t];
        i2t_q[t] = 1.f / (2.f * ta * ta);
    }

    // persistent per-thread state
    int r_av = t >> 3, j = t & 7;       // softmax/AV mapping: 8 lanes per row
    int e0 = j * 8;
    int sgrp = t & 15, rgrp = t >> 4;   // score mapping: 2 rows x 4 cols per thread
    float accS[8], accP[8];
    #pragma unroll
    for (int x = 0; x < 8; ++x) { accS[x] = 0.f; accP[x] = 0.f; }
    float m_run = -INFINITY, sse = 0.f, spr = 0.f, sprg = 0.f;

    for (int tile = 0; tile < NT; ++tile) {
        int s0g = tile * ST;
        // ---- stage k (transposed), v, psi_s, th_s ----
        for (int x = t; x < ST * EE; x += 256) {
            int e = x & 63, s = x >> 6;
            kT[e][s] = kb[(size_t)(s0g + s) * CC + e];
        }
        for (int x = t; x < ST * EE / 4; x += 256) {
            int s = x >> 4, e4 = (x & 15) * 4;
            *(float4*)&vs[s][e4] = *(const float4*)&vb[(size_t)(s0g + s) * CC + e4];
        }
        if (t < ST) { psi_s[t] = psib[s0g + t]; th_s[t] = thb[s0g + t]; }
        __syncthreads();

        // ---- scores: 2x4 register tile ----
        {
            float a00 = 0.f, a01 = 0.f, a02 = 0.f, a03 = 0.f;
            float a10 = 0.f, a11 = 0.f, a12 = 0.f, a13 = 0.f;
            int r0 = 2 * rgrp, s0 = 4 * sgrp;
            #pragma unroll 8
            for (int e = 0; e < EE; ++e) {
                float2 qv = *(const float2*)&qT[e][r0];
                float4 kv = *(const float4*)&kT[e][s0];
                a00 += qv.x * kv.x; a01 += qv.x * kv.y; a02 += qv.x * kv.z; a03 += qv.x * kv.w;
                a10 += qv.y * kv.x; a11 += qv.y * kv.y; a12 += qv.y * kv.z; a13 += qv.y * kv.w;
            }
            float4 w0 = make_float4(a00, a01, a02, a03);
            float4 w1 = make_float4(a10, a11, a12, a13);
            w0.x *= 0.125f; w0.y *= 0.125f; w0.z *= 0.125f; w0.w *= 0.125f;
            w1.x *= 0.125f; w1.y *= 0.125f; w1.z *= 0.125f; w1.w *= 0.125f;
            *(float4*)&sc[r0][s0] = w0;
            *(float4*)&sc[r0 + 1][s0] = w1;
        }
        __syncthreads();

        // ---- softmax + prior/gate (8 lanes per row, strided s = j + 8*i) ----
        {
            float pv[8];
            float pm = -INFINITY;
            #pragma unroll
            for (int i = 0; i < 8; ++i) {
                pv[i] = sc[r_av][j + 8 * i];
                pm = fmaxf(pm, pv[i]);
            }
            pm = fmaxf(pm, __shfl_xor(pm, 1));
            pm = fmaxf(pm, __shfl_xor(pm, 2));
            pm = fmaxf(pm, __shfl_xor(pm, 4));
            float m_new = fmaxf(m_run, pm);
            float scale = __expf(m_run - m_new);
            float psir = psi_q[r_av], thr = th_q[r_av], i2t = i2t_q[r_av];
            float psum = 0.f, lpr = 0.f, lpg = 0.f;
            #pragma unroll
            for (int i = 0; i < 8; ++i) {
                int s = j + 8 * i;
                float p = __expf(pv[i] - m_new);
                sc[r_av][s] = p;
                psum += p;
                float d = psir - psi_s[s];
                float pr = __expf(-0.5f * d * d);
                float dp = __sinf(0.5f * (thr - th_s[s]));
                float g = __expf(-dp * dp * i2t);
                float pgv = pr * g;
                pg[r_av][s] = pgv;
                lpr += pr; lpg += pgv;
            }
            m_run = m_new;
            sse = sse * scale + psum;
            spr += lpr; sprg += lpg;
            #pragma unroll
            for (int x = 0; x < 8; ++x) accS[x] *= scale;
        }
        __syncthreads();

        // ---- AV accumulate ----
        #pragma unroll 4
        for (int s = 0; s < ST; ++s) {
            float w = sc[r_av][s];
            float pw = pg[r_av][s];
            float4 v0 = *(const float4*)&vs[s][e0];
            float4 v1 = *(const float4*)&vs[s][e0 + 4];
            accS[0] += w * v0.x; accS[1] += w * v0.y; accS[2] += w * v0.z; accS[3] += w * v0.w;
            accS[4] += w * v1.x; accS[5] += w * v1.y; accS[6] += w * v1.z; accS[7] += w * v1.w;
            accP[0] += pw * v0.x; accP[1] += pw * v0.y; accP[2] += pw * v0.z; accP[3] += pw * v0.w;
            accP[4] += pw * v1.x; accP[5] += pw * v1.y; accP[6] += pw * v1.z; accP[7] += pw * v1.w;
        }
        __syncthreads();
    }

    // ---- epilogue: reduce row sums across the 8 lanes, combine, store ----
    sse += __shfl_xor(sse, 1); sse += __shfl_xor(sse, 2); sse += __shfl_xor(sse, 4);
    spr += __shfl_xor(spr, 1); spr += __shfl_xor(spr, 2); spr += __shfl_xor(spr, 4);
    sprg += __shfl_xor(sprg, 1); sprg += __shfl_xor(sprg, 2); sprg += __shfl_xor(sprg, 4);
    float cs = 0.9f / sse;
    float cp = 0.1f / (sprg + 1e-6f * (spr + 1e-6f));
    float* ob = out + (size_t)b * LL * CC + (size_t)(l0 + r_av) * CC + (size_t)h * EE + e0;
    float4 o0, o1;
    o0.x = cs * accS[0] + cp * accP[0]; o0.y = cs * accS[1] + cp * accP[1];
    o0.z = cs * accS[2] + cp * accP[2]; o0.w = cs * accS[3] + cp * accP[3];
    o1.x = cs * accS[4] + cp * accP[4]; o1.y = cs * accS[5] + cp * accP[5];
    o1.z = cs * accS[6] + cp * accP[6]; o1.w = cs * accS[7] + cp * accP[7];
    *(float4*)&ob[0] = o0;
    *(float4*)&ob[4] = o1;
}

extern "C" void kernel_launch(void* const* d_in, const int* in_sizes, int n_in,
                              void* d_out, int out_size, void* d_ws, size_t ws_size,
                              hipStream_t stream) {
    const float* q = (const float*)d_in[0];
    const float* k = (const float*)d_in[1];
    const float* v = (const float*)d_in[2];
    // d_in[3] = sigma (unused by the reference)
    const float* hurst = (const float*)d_in[4];
    const float* tau = (const float*)d_in[5];
    float* out = (float*)d_out;

    float* ws = (float*)d_ws;
    float* gi    = ws;                           // 1024
    float* psi   = gi + LL;                      // B*H*L
    float* taut  = psi + (size_t)BB * HH * LL;   // B*H*L
    float* theta = taut + (size_t)BB * HH * LL;  // B*L
    float* im    = theta + (size_t)BB * LL;      // L*C (one batch, reused)

    k_gi<<<1, LL, 0, stream>>>(gi);
    k_scan<<<BB * HH, LL, 0, stream>>>(hurst, tau, psi, taut);
    for (int b = 0; b < BB; b++) {
        dim3 gB(LL / 16, 8);
        k_hilb<<<gB, 256, 0, stream>>>(q, gi, im, b);
        k_theta<<<LL, 256, 0, stream>>>(q, im, theta, b);
    }
    k_attn<<<BB * HH * (LL / QT), 256, 0, stream>>>(q, k, v, psi, taut, theta, out);
}

// Round 4
// 464.908 us; speedup vs baseline: 7.2793x; 1.4939x over previous
//
#include <hip/hip_runtime.h>
#include <math.h>

#define LL 1024
#define BB 4
#define HH 8
#define EE 64
#define CC (HH*EE)  // 512

#define QT 32       // query rows per block
#define ST 64       // key/value tile
#define NT (LL/ST)  // 16 tiles

// ---------------- kernel 1: Hilbert circular-conv kernel table ----------------
// gi[d] = (2/L)*cot(pi*d/L) for odd d, else 0.
__global__ void k_gi(float* gi) {
    int d = blockIdx.x * blockDim.x + threadIdx.x;
    if (d >= LL) return;
    float v = 0.f;
    if (d & 1) {
        float a = 3.14159265358979323846f * (float)d / (float)LL;
        v = (2.0f / (float)LL) * (cosf(a) / sinf(a));
    }
    gi[d] = v;
}

// ---------------- kernel 2: hurst->psi cumsum, tau_t ----------------
__global__ __launch_bounds__(1024) void k_scan(const float* __restrict__ hurst,
                                               const float* __restrict__ tau,
                                               float* __restrict__ psi,
                                               float* __restrict__ taut) {
    __shared__ float s[LL];
    int bh = blockIdx.x;
    int b = bh / HH, h = bh % HH;
    int l = threadIdx.x;
    float hu = hurst[((size_t)b * LL + l) * HH + h];
    float ht = 1.f / (1.f + expf(-hu)) * 0.99f + 0.01f;
    s[l] = expf(2.0f * ht);
    __syncthreads();
    for (int off = 1; off < LL; off <<= 1) {
        float t = (l >= off) ? s[l - off] : 0.f;
        __syncthreads();
        s[l] += t;
        __syncthreads();
    }
    psi[((size_t)b * HH + h) * LL + l] = s[l];
    float tv = tau[((size_t)b * LL + l) * HH + h];
    taut[((size_t)b * HH + h) * LL + l] = 1.f / (1.f + expf(-tv)) * 0.9f + 0.1f;
}

// ---------------- kernel 3: Hilbert conv over SCRAMBLED view + theta partials ----
// x[b,i,c] = q[b, l, h, e] with h=i>>7, l=((i&127)<<3)|(c>>6), e=c&63.
// im[i,c] = sum_m gi[(i-m) mod L] * x[b,m,c]; then per-(b,i,cy) partial sums of
// sin/cos(phase) over the 64 e lanes (wave reduce), written to part_s/part_c.
// Grid: (32, 8, 4); thread: 8 i-outputs via 15-reg sliding window over T.
__global__ __launch_bounds__(256) void k_hilb(const float* __restrict__ q,
                                              const float* __restrict__ gi,
                                              float* __restrict__ part_s,
                                              float* __restrict__ part_c) {
    __shared__ float T[2047];   // T[u] = gi[(1023-u) & 1023]
    int t = threadIdx.x;
    for (int x = t; x < 2047; x += 256) T[x] = gi[(1023 - x) & 1023];
    __syncthreads();
    int cy = blockIdx.y;          // c>>6
    int b  = blockIdx.z;
    int e  = t & 63;
    int tr = t >> 6;
    int ibase = blockIdx.x * 32 + tr * 8;
    const float* qb = q + (size_t)b * LL * CC;
    int baseoff = (cy << 9) + e;
    float acc[8];
    #pragma unroll
    for (int d = 0; d < 8; ++d) acc[d] = 0.f;
    int ub = 1023 - ibase;        // >= 7
    float w[15];
    #pragma unroll
    for (int x = 0; x < 7; ++x) w[x] = T[ub - 7 + x];
    for (int m0 = 0; m0 < LL; m0 += 8) {
        #pragma unroll
        for (int j = 0; j < 8; ++j) w[7 + j] = T[m0 + ub + j];
        int off0 = ((m0 & 127) << 12) + ((m0 >> 7) << 6) + baseoff;
        float xv[8];
        #pragma unroll
        for (int j = 0; j < 8; ++j) xv[j] = qb[off0 + (j << 12)];
        #pragma unroll
        for (int j = 0; j < 8; ++j) {
            #pragma unroll
            for (int d = 0; d < 8; ++d) acc[d] += w[7 + j - d] * xv[j];
        }
        #pragma unroll
        for (int x = 0; x < 7; ++x) w[x] = w[x + 8];
    }
    // theta partials: phase = atan2(iv, re); accumulate sin,cos over e lanes
    #pragma unroll
    for (int d = 0; d < 8; ++d) {
        int i = ibase + d;
        float iv = acc[d];
        float re = qb[((i & 127) << 12) + ((i >> 7) << 6) + baseoff];
        float r = sqrtf(re * re + iv * iv);
        float sv, cv;
        if (r > 0.f) { sv = iv / r; cv = re / r; }
        else { sv = 0.f; cv = 1.f; }
        #pragma unroll
        for (int m = 1; m < 64; m <<= 1) {
            sv += __shfl_xor(sv, m);
            cv += __shfl_xor(cv, m);
        }
        if (e == 0) {
            size_t o = (((size_t)b << 10) + i) * 8 + cy;
            part_s[o] = sv;
            part_c[o] = cv;
        }
    }
}

// ---------------- kernel 4: finalize theta ----------------
__global__ __launch_bounds__(256) void k_theta_fin(const float* __restrict__ part_s,
                                                   const float* __restrict__ part_c,
                                                   float* __restrict__ theta) {
    int tid = blockIdx.x * 256 + threadIdx.x;   // b*1024 + i
    if (tid >= BB * LL) return;
    float ss = 0.f, cc = 0.f;
    #pragma unroll
    for (int cy = 0; cy < 8; ++cy) {
        ss += part_s[(size_t)tid * 8 + cy];
        cc += part_c[(size_t)tid * 8 + cy];
    }
    theta[tid] = atan2f(ss, cc);
}

// ---------------- kernel 5: tiled fused attention, register softmax ----------------
// thread (rgrp=t>>4, sgrp=t&15): rows r0=2*rgrp..+1, cols s0=4*sgrp..+3,
// output e-range 4*sgrp..+3. LDS swizzled in float4 slots.
__global__ __launch_bounds__(256) void k_attn(const float* __restrict__ q,
                                              const float* __restrict__ k,
                                              const float* __restrict__ v,
                                              const float* __restrict__ psi,
                                              const float* __restrict__ taut,
                                              const float* __restrict__ theta,
                                              float* __restrict__ out) {
    __shared__ float qs[QT * EE];
    __shared__ float ks[ST * EE];
    __shared__ float vsm[ST * EE];
    __shared__ float psi_s[ST], th_s[ST];
    __shared__ float psi_q[QT], th_q[QT], i2t_q[QT];
    float4* qs4 = (float4*)qs;
    float4* ks4 = (float4*)ks;
    float4* vs4 = (float4*)vsm;

    int t = threadIdx.x;
    int blk = blockIdx.x;
    int qt = blk & (LL / QT - 1);
    int bh = blk >> 5;
    int h = bh & (HH - 1), b = bh >> 3;
    int l0 = qt * QT;

    int sgrp = t & 15, rgrp = t >> 4;
    int r0 = rgrp * 2, s0 = sgrp * 4;

    const float* qbase = q + (size_t)b * LL * CC + (size_t)l0 * CC + (size_t)h * EE;
    const float* kb = k + (size_t)b * LL * CC + (size_t)h * EE;
    const float* vb = v + (size_t)b * LL * CC + (size_t)h * EE;
    const float* psib = psi + (size_t)bh * LL;
    const float* thb = theta + (size_t)b * LL;

    // stage q (swizzled: slot ^= r&7)
    for (int x = t; x < QT * 16; x += 256) {
        int r = x >> 4, ec = x & 15;
        qs4[r * 16 + (ec ^ (r & 7))] = *(const float4*)&qbase[(size_t)r * CC + ec * 4];
    }
    if (t < QT) {
        psi_q[t] = psib[l0 + t];
        th_q[t] = thb[l0 + t];
        float ta = taut[(size_t)bh * LL + l0 + t];
        i2t_q[t] = 1.f / (2.f * ta * ta);
    }
    __syncthreads();
    float psiq0 = psi_q[r0], psiq1 = psi_q[r0 + 1];
    float thq0 = th_q[r0], thq1 = th_q[r0 + 1];
    float i2t0 = i2t_q[r0], i2t1 = i2t_q[r0 + 1];

    float accS0[4], accS1[4], accP0[4], accP1[4];
    #pragma unroll
    for (int c = 0; c < 4; ++c) { accS0[c] = 0.f; accS1[c] = 0.f; accP0[c] = 0.f; accP1[c] = 0.f; }
    float m0r = -INFINITY, m1r = -INFINITY;
    float sse0 = 0.f, sse1 = 0.f, spr0 = 0.f, spr1 = 0.f, spg0 = 0.f, spg1 = 0.f;
    int lanebase = t & 48;

    for (int tile = 0; tile < NT; ++tile) {
        int s0g = tile * ST;
        // stage k (slot ^= (s>>2)&7), v (slot ^= s&7)
        for (int x = t; x < ST * 16; x += 256) {
            int s = x >> 4, ec = x & 15;
            ks4[s * 16 + (ec ^ ((s >> 2) & 7))] = *(const float4*)&kb[(size_t)(s0g + s) * CC + ec * 4];
            vs4[s * 16 + (ec ^ (s & 7))] = *(const float4*)&vb[(size_t)(s0g + s) * CC + ec * 4];
        }
        if (t < ST) { psi_s[t] = psib[s0g + t]; th_s[t] = thb[s0g + t]; }
        __syncthreads();

        // ---- scores ----
        float a0[4], a1[4];
        #pragma unroll
        for (int i = 0; i < 4; ++i) { a0[i] = 0.f; a1[i] = 0.f; }
        #pragma unroll 4
        for (int ec = 0; ec < 16; ++ec) {
            float4 q0 = qs4[r0 * 16 + (ec ^ (r0 & 7))];
            float4 q1 = qs4[(r0 + 1) * 16 + (ec ^ ((r0 + 1) & 7))];
            int kslot = ec ^ (sgrp & 7);
            float4 k0 = ks4[(s0 + 0) * 16 + kslot];
            float4 k1 = ks4[(s0 + 1) * 16 + kslot];
            float4 k2 = ks4[(s0 + 2) * 16 + kslot];
            float4 k3 = ks4[(s0 + 3) * 16 + kslot];
            a0[0] += q0.x*k0.x + q0.y*k0.y + q0.z*k0.z + q0.w*k0.w;
            a0[1] += q0.x*k1.x + q0.y*k1.y + q0.z*k1.z + q0.w*k1.w;
            a0[2] += q0.x*k2.x + q0.y*k2.y + q0.z*k2.z + q0.w*k2.w;
            a0[3] += q0.x*k3.x + q0.y*k3.y + q0.z*k3.z + q0.w*k3.w;
            a1[0] += q1.x*k0.x + q1.y*k0.y + q1.z*k0.z + q1.w*k0.w;
            a1[1] += q1.x*k1.x + q1.y*k1.y + q1.z*k1.z + q1.w*k1.w;
            a1[2] += q1.x*k2.x + q1.y*k2.y + q1.z*k2.z + q1.w*k2.w;
            a1[3] += q1.x*k3.x + q1.y*k3.y + q1.z*k3.z + q1.w*k3.w;
        }
        #pragma unroll
        for (int i = 0; i < 4; ++i) { a0[i] *= 0.125f; a1[i] *= 0.125f; }

        // ---- online softmax (register) ----
        float pm0 = fmaxf(fmaxf(a0[0], a0[1]), fmaxf(a0[2], a0[3]));
        float pm1 = fmaxf(fmaxf(a1[0], a1[1]), fmaxf(a1[2], a1[3]));
        #pragma unroll
        for (int m = 1; m < 16; m <<= 1) {
            pm0 = fmaxf(pm0, __shfl_xor(pm0, m));
            pm1 = fmaxf(pm1, __shfl_xor(pm1, m));
        }
        float mn0 = fmaxf(m0r, pm0), mn1 = fmaxf(m1r, pm1);
        float sc0 = __expf(m0r - mn0), sc1 = __expf(m1r - mn1);
        m0r = mn0; m1r = mn1;
        float b0[4], b1[4];
        float psum0 = 0.f, psum1 = 0.f;
        #pragma unroll
        for (int i = 0; i < 4; ++i) {
            int s = s0 + i;
            a0[i] = __expf(a0[i] - mn0); psum0 += a0[i];
            a1[i] = __expf(a1[i] - mn1); psum1 += a1[i];
            float pss = psi_s[s], ths = th_s[s];
            float d0 = psiq0 - pss;
            float pr0 = __expf(-0.5f * d0 * d0);
            float dp0 = __sinf(0.5f * (thq0 - ths));
            float g0 = __expf(-dp0 * dp0 * i2t0);
            b0[i] = pr0 * g0; spr0 += pr0; spg0 += b0[i];
            float d1 = psiq1 - pss;
            float pr1 = __expf(-0.5f * d1 * d1);
            float dp1 = __sinf(0.5f * (thq1 - ths));
            float g1 = __expf(-dp1 * dp1 * i2t1);
            b1[i] = pr1 * g1; spr1 += pr1; spg1 += b1[i];
        }
        sse0 = sse0 * sc0 + psum0;
        sse1 = sse1 * sc1 + psum1;
        #pragma unroll
        for (int c = 0; c < 4; ++c) { accS0[c] *= sc0; accS1[c] *= sc1; }

        // ---- AV: broadcast p/pg via shfl, accumulate ----
        for (int s4 = 0; s4 < 16; ++s4) {
            int src = lanebase + s4;
            #pragma unroll
            for (int i = 0; i < 4; ++i) {
                int s = s4 * 4 + i;
                float wS0 = __shfl(a0[i], src);
                float wS1 = __shfl(a1[i], src);
                float wP0 = __shfl(b0[i], src);
                float wP1 = __shfl(b1[i], src);
                float4 v4 = vs4[s * 16 + (sgrp ^ (s & 7))];
                accS0[0] += wS0 * v4.x; accS0[1] += wS0 * v4.y; accS0[2] += wS0 * v4.z; accS0[3] += wS0 * v4.w;
                accS1[0] += wS1 * v4.x; accS1[1] += wS1 * v4.y; accS1[2] += wS1 * v4.z; accS1[3] += wS1 * v4.w;
                accP0[0] += wP0 * v4.x; accP0[1] += wP0 * v4.y; accP0[2] += wP0 * v4.z; accP0[3] += wP0 * v4.w;
                accP1[0] += wP1 * v4.x; accP1[1] += wP1 * v4.y; accP1[2] += wP1 * v4.z; accP1[3] += wP1 * v4.w;
            }
        }
        __syncthreads();
    }

    // ---- epilogue ----
    #pragma unroll
    for (int m = 1; m < 16; m <<= 1) {
        sse0 += __shfl_xor(sse0, m); sse1 += __shfl_xor(sse1, m);
        spr0 += __shfl_xor(spr0, m); spr1 += __shfl_xor(spr1, m);
        spg0 += __shfl_xor(spg0, m); spg1 += __shfl_xor(spg1, m);
    }
    float cs0 = 0.9f / sse0, cs1 = 0.9f / sse1;
    float cp0 = 0.1f / (spg0 + 1e-6f * (spr0 + 1e-6f));
    float cp1 = 0.1f / (spg1 + 1e-6f * (spr1 + 1e-6f));
    float* ob0 = out + (size_t)b * LL * CC + (size_t)(l0 + r0) * CC + (size_t)h * EE + s0;
    float* ob1 = ob0 + CC;
    float4 o0, o1;
    o0.x = cs0 * accS0[0] + cp0 * accP0[0];
    o0.y = cs0 * accS0[1] + cp0 * accP0[1];
    o0.z = cs0 * accS0[2] + cp0 * accP0[2];
    o0.w = cs0 * accS0[3] + cp0 * accP0[3];
    o1.x = cs1 * accS1[0] + cp1 * accP1[0];
    o1.y = cs1 * accS1[1] + cp1 * accP1[1];
    o1.z = cs1 * accS1[2] + cp1 * accP1[2];
    o1.w = cs1 * accS1[3] + cp1 * accP1[3];
    *(float4*)ob0 = o0;
    *(float4*)ob1 = o1;
}

extern "C" void kernel_launch(void* const* d_in, const int* in_sizes, int n_in,
                              void* d_out, int out_size, void* d_ws, size_t ws_size,
                              hipStream_t stream) {
    const float* q = (const float*)d_in[0];
    const float* k = (const float*)d_in[1];
    const float* v = (const float*)d_in[2];
    // d_in[3] = sigma (unused by the reference)
    const float* hurst = (const float*)d_in[4];
    const float* tau = (const float*)d_in[5];
    float* out = (float*)d_out;

    float* ws = (float*)d_ws;
    float* gi     = ws;                            // 1024
    float* psi    = gi + LL;                       // 32768
    float* taut   = psi + (size_t)BB * HH * LL;    // 32768
    float* theta  = taut + (size_t)BB * HH * LL;   // 4096
    float* part_s = theta + (size_t)BB * LL;       // 32768
    float* part_c = part_s + (size_t)BB * LL * 8;  // 32768

    k_gi<<<1, LL, 0, stream>>>(gi);
    k_scan<<<BB * HH, LL, 0, stream>>>(hurst, tau, psi, taut);
    dim3 gH(LL / 32, 8, BB);
    k_hilb<<<gH, 256, 0, stream>>>(q, gi, part_s, part_c);
    k_theta_fin<<<(BB * LL) / 256, 256, 0, stream>>>(part_s, part_c, theta);
    k_attn<<<BB * HH * (LL / QT), 256, 0, stream>>>(q, k, v, psi, taut, theta, out);
}

// Round 5
// 192.655 us; speedup vs baseline: 17.5661x; 2.4132x over previous
//
#include <hip/hip_runtime.h>
#include <math.h>

#define LL 1024
#define BB 4
#define HH 8
#define EE 64
#define CC (HH*EE)  // 512

typedef __attribute__((ext_vector_type(4))) float f32x4;
typedef __attribute__((ext_vector_type(8))) short bf16x8;
typedef __attribute__((ext_vector_type(4))) short bf16x4;

__device__ __forceinline__ unsigned short f2bf(float x) {
    unsigned u = __float_as_uint(x);
    u += 0x7FFFu + ((u >> 16) & 1u);   // round-to-nearest-even
    return (unsigned short)(u >> 16);
}

// ---------------- kernel 1: Hilbert circular-conv kernel table ----------------
__global__ void k_gi(float* gi) {
    int d = blockIdx.x * blockDim.x + threadIdx.x;
    if (d >= LL) return;
    float v = 0.f;
    if (d & 1) {
        float a = 3.14159265358979323846f * (float)d / (float)LL;
        v = (2.0f / (float)LL) * (cosf(a) / sinf(a));
    }
    gi[d] = v;
}

// ---------------- kernel 2: hurst->psi cumsum, tau_t ----------------
__global__ __launch_bounds__(1024) void k_scan(const float* __restrict__ hurst,
                                               const float* __restrict__ tau,
                                               float* __restrict__ psi,
                                               float* __restrict__ taut) {
    __shared__ float s[LL];
    int bh = blockIdx.x;
    int b = bh / HH, h = bh % HH;
    int l = threadIdx.x;
    float hu = hurst[((size_t)b * LL + l) * HH + h];
    float ht = 1.f / (1.f + expf(-hu)) * 0.99f + 0.01f;
    s[l] = expf(2.0f * ht);
    __syncthreads();
    for (int off = 1; off < LL; off <<= 1) {
        float t = (l >= off) ? s[l - off] : 0.f;
        __syncthreads();
        s[l] += t;
        __syncthreads();
    }
    psi[((size_t)b * HH + h) * LL + l] = s[l];
    float tv = tau[((size_t)b * LL + l) * HH + h];
    taut[((size_t)b * HH + h) * LL + l] = 1.f / (1.f + expf(-tv)) * 0.9f + 0.1f;
}

// ---------------- kernel 3: Hilbert conv over SCRAMBLED view + theta partials ----
__global__ __launch_bounds__(256) void k_hilb(const float* __restrict__ q,
                                              const float* __restrict__ gi,
                                              float* __restrict__ part_s,
                                              float* __restrict__ part_c) {
    __shared__ float T[2047];   // T[u] = gi[(1023-u) & 1023]
    int t = threadIdx.x;
    for (int x = t; x < 2047; x += 256) T[x] = gi[(1023 - x) & 1023];
    __syncthreads();
    int cy = blockIdx.y;
    int b  = blockIdx.z;
    int e  = t & 63;
    int tr = t >> 6;
    int ibase = blockIdx.x * 32 + tr * 8;
    const float* qb = q + (size_t)b * LL * CC;
    int baseoff = (cy << 9) + e;
    float acc[8];
    #pragma unroll
    for (int d = 0; d < 8; ++d) acc[d] = 0.f;
    int ub = 1023 - ibase;
    float w[15];
    #pragma unroll
    for (int x = 0; x < 7; ++x) w[x] = T[ub - 7 + x];
    for (int m0 = 0; m0 < LL; m0 += 8) {
        #pragma unroll
        for (int j = 0; j < 8; ++j) w[7 + j] = T[m0 + ub + j];
        int off0 = ((m0 & 127) << 12) + ((m0 >> 7) << 6) + baseoff;
        float xv[8];
        #pragma unroll
        for (int j = 0; j < 8; ++j) xv[j] = qb[off0 + (j << 12)];
        #pragma unroll
        for (int j = 0; j < 8; ++j) {
            #pragma unroll
            for (int d = 0; d < 8; ++d) acc[d] += w[7 + j - d] * xv[j];
        }
        #pragma unroll
        for (int x = 0; x < 7; ++x) w[x] = w[x + 8];
    }
    #pragma unroll
    for (int d = 0; d < 8; ++d) {
        int i = ibase + d;
        float iv = acc[d];
        float re = qb[((i & 127) << 12) + ((i >> 7) << 6) + baseoff];
        float r = sqrtf(re * re + iv * iv);
        float sv, cv;
        if (r > 0.f) { sv = iv / r; cv = re / r; }
        else { sv = 0.f; cv = 1.f; }
        #pragma unroll
        for (int m = 1; m < 64; m <<= 1) {
            sv += __shfl_xor(sv, m);
            cv += __shfl_xor(cv, m);
        }
        if (e == 0) {
            size_t o = (((size_t)b << 10) + i) * 8 + cy;
            part_s[o] = sv;
            part_c[o] = cv;
        }
    }
}

// ---------------- kernel 4: finalize theta ----------------
__global__ __launch_bounds__(256) void k_theta_fin(const float* __restrict__ part_s,
                                                   const float* __restrict__ part_c,
                                                   float* __restrict__ theta) {
    int tid = blockIdx.x * 256 + threadIdx.x;
    if (tid >= BB * LL) return;
    float ss = 0.f, cc = 0.f;
    #pragma unroll
    for (int cy = 0; cy < 8; ++cy) {
        ss += part_s[(size_t)tid * 8 + cy];
        cc += part_c[(size_t)tid * 8 + cy];
    }
    theta[tid] = atan2f(ss, cc);
}

// ---------------- kernel 5: MFMA flash attention ----------------
// Block: 256 thr = 4 waves, 64 q-rows (16/wave). 16 s-tiles of 64.
// S^T = mfma(K, Q) -> lane owns 16 scores of q-row (lane&15).
// P/PG C-frag regs feed PV A-frags directly (slot j -> s = 4g+(j&3)+16(j>>2)).
__global__ __launch_bounds__(256) void k_attn(const float* __restrict__ q,
                                              const float* __restrict__ k,
                                              const float* __restrict__ v,
                                              const float* __restrict__ psi,
                                              const float* __restrict__ taut,
                                              const float* __restrict__ theta,
                                              float* __restrict__ out) {
    __shared__ unsigned short q_lds[64][64];   // bf16, granule-swizzled
    __shared__ unsigned short k_lds[64][64];   // bf16, granule-swizzled
    __shared__ unsigned short v_sub[4][16][16][4]; // [e>>4][s>>2][e&15][s&3]
    __shared__ float psi_s[64], th_s[64];

    int t = threadIdx.x;
    int lid = t & 63;
    int wv = t >> 6;
    int m16 = lid & 15;
    int g = lid >> 4;

    int blk = blockIdx.x;
    int qt = blk & 15;
    int bh = blk >> 4;
    int h = bh & 7, b = bh >> 3;
    int l0 = qt * 64;

    const float* qg = q + ((size_t)(b * LL + l0) * CC + (size_t)h * EE);
    const float* kg = k + ((size_t)b * LL * CC + (size_t)h * EE);
    const float* vg = v + ((size_t)b * LL * CC + (size_t)h * EE);
    const float* psib = psi + (size_t)bh * LL;
    const float* thb = theta + (size_t)b * LL;

    // per-lane q-row constants (this lane's softmax row: q0W + m16)
    int qrow = wv * 16 + m16;
    float psiq = psib[l0 + qrow];
    float thq  = thb[l0 + qrow];
    float ta   = taut[(size_t)bh * LL + l0 + qrow];
    float i2t  = 1.f / (2.f * ta * ta);

    // ---- stage Q (x0.125 folded in, exact) ----
    #pragma unroll
    for (int it = 0; it < 2; ++it) {
        int flat = it * 256 + t;
        int row = flat >> 3, gr = flat & 7;
        const float* src = qg + (size_t)row * CC + gr * 8;
        float4 a4 = *(const float4*)src;
        float4 b4 = *(const float4*)(src + 4);
        int pos = gr ^ (row & 7);
        bf16x8 kv;
        kv[0] = (short)f2bf(0.125f * a4.x); kv[1] = (short)f2bf(0.125f * a4.y);
        kv[2] = (short)f2bf(0.125f * a4.z); kv[3] = (short)f2bf(0.125f * a4.w);
        kv[4] = (short)f2bf(0.125f * b4.x); kv[5] = (short)f2bf(0.125f * b4.y);
        kv[6] = (short)f2bf(0.125f * b4.z); kv[7] = (short)f2bf(0.125f * b4.w);
        *(bf16x8*)&q_lds[row][pos * 8] = kv;
    }
    __syncthreads();

    // ---- load Q B-frags (persistent): lane holds Q[e=32ec+8g+j][q0W+m16] ----
    bf16x8 qf[2];
    #pragma unroll
    for (int ec = 0; ec < 2; ++ec) {
        int pos = (4 * ec + g) ^ (m16 & 7);
        qf[ec] = *(bf16x8*)&q_lds[wv * 16 + m16][pos * 8];
    }

    f32x4 accS[4], accP[4];
    #pragma unroll
    for (int f = 0; f < 4; ++f) {
        accS[f] = (f32x4){0.f, 0.f, 0.f, 0.f};
        accP[f] = (f32x4){0.f, 0.f, 0.f, 0.f};
    }
    float mrun = -INFINITY, ssel = 0.f, sprl = 0.f, spgl = 0.f;

    for (int tile = 0; tile < 16; ++tile) {
        if (tile) __syncthreads();
        int s0g = tile * 64;

        // stage K (bf16, swizzled)
        #pragma unroll
        for (int it = 0; it < 2; ++it) {
            int flat = it * 256 + t;
            int row = flat >> 3, gr = flat & 7;
            const float* src = kg + (size_t)(s0g + row) * CC + gr * 8;
            float4 a4 = *(const float4*)src;
            float4 b4 = *(const float4*)(src + 4);
            int pos = gr ^ (row & 7);
            bf16x8 kv;
            kv[0] = (short)f2bf(a4.x); kv[1] = (short)f2bf(a4.y);
            kv[2] = (short)f2bf(a4.z); kv[3] = (short)f2bf(a4.w);
            kv[4] = (short)f2bf(b4.x); kv[5] = (short)f2bf(b4.y);
            kv[6] = (short)f2bf(b4.z); kv[7] = (short)f2bf(b4.w);
            *(bf16x8*)&k_lds[row][pos * 8] = kv;
        }
        // stage V subtiled (bf16 transpose scatter)
        #pragma unroll
        for (int it = 0; it < 4; ++it) {
            int flat = it * 256 + t;
            int s = flat >> 4, i = flat & 15;
            float4 a4 = *(const float4*)(vg + (size_t)(s0g + s) * CC + i * 4);
            int eb = i >> 2, e4 = (i & 3) * 4, sg = s >> 2, sl = s & 3;
            v_sub[eb][sg][e4 + 0][sl] = f2bf(a4.x);
            v_sub[eb][sg][e4 + 1][sl] = f2bf(a4.y);
            v_sub[eb][sg][e4 + 2][sl] = f2bf(a4.z);
            v_sub[eb][sg][e4 + 3][sl] = f2bf(a4.w);
        }
        if (t < 64) { psi_s[t] = psib[s0g + t]; th_s[t] = thb[s0g + t]; }
        __syncthreads();

        // ---- S^T: 4 s-frags x 2 e-chunks ----
        f32x4 st[4];
        #pragma unroll
        for (int f = 0; f < 4; ++f) st[f] = (f32x4){0.f, 0.f, 0.f, 0.f};
        #pragma unroll
        for (int ec = 0; ec < 2; ++ec) {
            int pos = (4 * ec + g) ^ (m16 & 7);
            #pragma unroll
            for (int f = 0; f < 4; ++f) {
                bf16x8 ka = *(bf16x8*)&k_lds[16 * f + m16][pos * 8];
                st[f] = __builtin_amdgcn_mfma_f32_16x16x32_bf16(ka, qf[ec], st[f], 0, 0, 0);
            }
        }

        // ---- online softmax + prior/gate (all for q-row = q0W+m16) ----
        float mx = st[0][0];
        #pragma unroll
        for (int f = 0; f < 4; ++f)
            #pragma unroll
            for (int r = 0; r < 4; ++r) mx = fmaxf(mx, st[f][r]);
        mx = fmaxf(mx, __shfl_xor(mx, 16));
        mx = fmaxf(mx, __shfl_xor(mx, 32));
        float mnew = fmaxf(mrun, mx);
        float scl = __expf(mrun - mnew);
        mrun = mnew;

        float psum = 0.f;
        unsigned short pb[16], gb[16];
        #pragma unroll
        for (int f = 0; f < 4; ++f) {
            float4 ps4 = *(const float4*)&psi_s[16 * f + 4 * g];
            float4 th4 = *(const float4*)&th_s[16 * f + 4 * g];
            float pss[4] = {ps4.x, ps4.y, ps4.z, ps4.w};
            float ths[4] = {th4.x, th4.y, th4.z, th4.w};
            #pragma unroll
            for (int r = 0; r < 4; ++r) {
                float p = __expf(st[f][r] - mnew);
                psum += p;
                float d = psiq - pss[r];
                float pr = __expf(-0.5f * d * d);
                float dp = __sinf(0.5f * (thq - ths[r]));
                float gg = __expf(-dp * dp * i2t);
                float pgv = pr * gg;
                sprl += pr; spgl += pgv;
                pb[f * 4 + r] = f2bf(p);
                gb[f * 4 + r] = f2bf(pgv);
            }
        }
        ssel = ssel * scl + psum;

        // rescale accS by per-row scale (row = 4g+r lives at lane 4g+r)
        float sr[4];
        #pragma unroll
        for (int r = 0; r < 4; ++r) sr[r] = __shfl(scl, 4 * g + r);
        #pragma unroll
        for (int f = 0; f < 4; ++f)
            #pragma unroll
            for (int r = 0; r < 4; ++r) accS[f][r] *= sr[r];

        // pack P / PG A-frags: chunk c slots j = {frag 2c regs, frag 2c+1 regs}
        bf16x8 pS[2], pG[2];
        #pragma unroll
        for (int c = 0; c < 2; ++c)
            #pragma unroll
            for (int j = 0; j < 8; ++j) {
                pS[c][j] = (short)pb[c * 8 + j];
                pG[c][j] = (short)gb[c * 8 + j];
            }

        // ---- PV: 2 chunks x 4 e-frags, V B-frag = 2x b64 conflict-free ----
        #pragma unroll
        for (int c = 0; c < 2; ++c) {
            #pragma unroll
            for (int ef = 0; ef < 4; ++ef) {
                bf16x4 v0 = *(bf16x4*)&v_sub[ef][8 * c + g][m16][0];
                bf16x4 v1 = *(bf16x4*)&v_sub[ef][8 * c + 4 + g][m16][0];
                bf16x8 vb;
                vb[0] = v0[0]; vb[1] = v0[1]; vb[2] = v0[2]; vb[3] = v0[3];
                vb[4] = v1[0]; vb[5] = v1[1]; vb[6] = v1[2]; vb[7] = v1[3];
                accS[ef] = __builtin_amdgcn_mfma_f32_16x16x32_bf16(pS[c], vb, accS[ef], 0, 0, 0);
                accP[ef] = __builtin_amdgcn_mfma_f32_16x16x32_bf16(pG[c], vb, accP[ef], 0, 0, 0);
            }
        }
    }

    // ---- epilogue ----
    ssel += __shfl_xor(ssel, 16); ssel += __shfl_xor(ssel, 32);
    sprl += __shfl_xor(sprl, 16); sprl += __shfl_xor(sprl, 32);
    spgl += __shfl_xor(spgl, 16); spgl += __shfl_xor(spgl, 32);
    float cs = 0.9f / ssel;
    float cp = 0.1f / (spgl + 1e-6f * (sprl + 1e-6f));
    float* ob = out + ((size_t)(b * LL + l0 + wv * 16) * CC + (size_t)h * EE);
    #pragma unroll
    for (int r = 0; r < 4; ++r) {
        float csr = __shfl(cs, 4 * g + r);
        float cpr = __shfl(cp, 4 * g + r);
        #pragma unroll
        for (int f = 0; f < 4; ++f) {
            ob[(size_t)(4 * g + r) * CC + 16 * f + m16] =
                csr * accS[f][r] + cpr * accP[f][r];
        }
    }
}

extern "C" void kernel_launch(void* const* d_in, const int* in_sizes, int n_in,
                              void* d_out, int out_size, void* d_ws, size_t ws_size,
                              hipStream_t stream) {
    const float* q = (const float*)d_in[0];
    const float* k = (const float*)d_in[1];
    const float* v = (const float*)d_in[2];
    // d_in[3] = sigma (unused by the reference)
    const float* hurst = (const float*)d_in[4];
    const float* tau = (const float*)d_in[5];
    float* out = (float*)d_out;

    float* ws = (float*)d_ws;
    float* gi     = ws;                            // 1024
    float* psi    = gi + LL;                       // 32768
    float* taut   = psi + (size_t)BB * HH * LL;    // 32768
    float* theta  = taut + (size_t)BB * HH * LL;   // 4096
    float* part_s = theta + (size_t)BB * LL;       // 32768
    float* part_c = part_s + (size_t)BB * LL * 8;  // 32768

    k_gi<<<1, LL, 0, stream>>>(gi);
    k_scan<<<BB * HH, LL, 0, stream>>>(hurst, tau, psi, taut);
    dim3 gH(LL / 32, 8, BB);
    k_hilb<<<gH, 256, 0, stream>>>(q, gi, part_s, part_c);
    k_theta_fin<<<(BB * LL) / 256, 256, 0, stream>>>(part_s, part_c, theta);
    k_attn<<<BB * HH * (LL / 64), 256, 0, stream>>>(q, k, v, psi, taut, theta, out);
}

// Round 6
// 127.854 us; speedup vs baseline: 26.4692x; 1.5068x over previous
//
#include <hip/hip_runtime.h>
#include <math.h>

#define LL 1024
#define BB 4
#define HH 8
#define EE 64
#define CC (HH*EE)  // 512

typedef __attribute__((ext_vector_type(4))) float f32x4;
typedef __attribute__((ext_vector_type(8))) short bf16x8;
typedef __attribute__((ext_vector_type(4))) short bf16x4;

__device__ __forceinline__ unsigned short f2bf(float x) {
    unsigned u = __float_as_uint(x);
    u += 0x7FFFu + ((u >> 16) & 1u);   // round-to-nearest-even
    return (unsigned short)(u >> 16);
}

// ---------------- kernel 1: Hilbert circular-conv kernel table ----------------
__global__ void k_gi(float* gi) {
    int d = blockIdx.x * blockDim.x + threadIdx.x;
    if (d >= LL) return;
    float v = 0.f;
    if (d & 1) {
        float a = 3.14159265358979323846f * (float)d / (float)LL;
        v = (2.0f / (float)LL) * (cosf(a) / sinf(a));
    }
    gi[d] = v;
}

// ---------------- kernel 2: hurst->psi cumsum, tau_t ----------------
__global__ __launch_bounds__(1024) void k_scan(const float* __restrict__ hurst,
                                               const float* __restrict__ tau,
                                               float* __restrict__ psi,
                                               float* __restrict__ taut) {
    __shared__ float s[LL];
    int bh = blockIdx.x;
    int b = bh / HH, h = bh % HH;
    int l = threadIdx.x;
    float hu = hurst[((size_t)b * LL + l) * HH + h];
    float ht = 1.f / (1.f + expf(-hu)) * 0.99f + 0.01f;
    s[l] = expf(2.0f * ht);
    __syncthreads();
    for (int off = 1; off < LL; off <<= 1) {
        float t = (l >= off) ? s[l - off] : 0.f;
        __syncthreads();
        s[l] += t;
        __syncthreads();
    }
    psi[((size_t)b * HH + h) * LL + l] = s[l];
    float tv = tau[((size_t)b * LL + l) * HH + h];
    taut[((size_t)b * HH + h) * LL + l] = 1.f / (1.f + expf(-tv)) * 0.9f + 0.1f;
}

// ---------------- kernel 3: MFMA Hilbert conv (split bf16 GEMM) + theta partials
// C[i,n] = sum_k G[i,k]*x[k,n], G[i,k]=gi[(i-k)&1023] circulant,
// x[k,n] = scrambled q view: n = b*512+c, x = q[b][((k&127)<<3)|(c>>6)][k>>7][c&63].
// 3-product split GEMM (Gh*xh + Gh*xl + Gl*xh) for ~fp32 accuracy.
// Block: 64 i x 128 n, K-tiles of 64. 4 waves in 2x2 (wi,wn).
// Epilogue: theta sin/cos partials over the block's 128 channels.
__global__ __launch_bounds__(256) void k_hilb(const float* __restrict__ q,
                                              const float* __restrict__ gi,
                                              float* __restrict__ part_s,
                                              float* __restrict__ part_c) {
    __shared__ unsigned short strip_hi[1024], strip_lo[1024];
    __shared__ unsigned short A_hi[64][64], A_lo[64][64];
    __shared__ unsigned short xh[8][16][16][4], xl[8][16][16][4];
    __shared__ float psv[4][32], pcv[4][32];

    int t = threadIdx.x;
    int lid = t & 63;
    int wv = t >> 6;
    int m16 = lid & 15;
    int g = lid >> 4;
    int wi = wv >> 1, wn = wv & 1;

    // XCD-aware mapping: each XCD (bid%8) owns 4 n-panels x 8 i-panels
    int bid = blockIdx.x;
    int xcd = bid & 7, o = bid >> 3;
    int im = ((xcd >> 2) << 3) + (o & 7);   // 0..15
    int in = ((xcd & 3) << 2) + (o >> 3);   // 0..15
    int i0 = im * 64, n0 = in * 128;
    int bq = n0 >> 9;
    int cy0 = (n0 & 511) >> 6;
    int quad = in & 3;

    const float* qb = q + (size_t)bq * LL * CC;

    // prefetch tile 0 while building tables
    float4 xs[8];
    {
        #pragma unroll
        for (int it = 0; it < 8; ++it) {
            int f = it * 256 + t;
            int kk = f >> 5, f4 = f & 31;
            int nl = f4 * 4;
            int kgl = kk;
            int cy = cy0 + (nl >> 6);
            int l = ((kgl & 127) << 3) | cy;
            int h2 = kgl >> 7;
            xs[it] = *(const float4*)(qb + l * 512 + h2 * 64 + (nl & 63));
        }
    }
    // bf16 hi/lo split tables of gi
    for (int x = t; x < 1024; x += 256) {
        float gg = gi[x];
        unsigned short h = f2bf(gg);
        float hf = __uint_as_float(((unsigned)h) << 16);
        strip_hi[x] = h;
        strip_lo[x] = f2bf(gg - hf);
    }
    __syncthreads();

    f32x4 acc[2][4];
    #pragma unroll
    for (int mf = 0; mf < 2; ++mf)
        #pragma unroll
        for (int nf = 0; nf < 4; ++nf) acc[mf][nf] = (f32x4){0.f, 0.f, 0.f, 0.f};

    for (int kt = 0; kt < 16; ++kt) {
        if (kt) __syncthreads();   // previous compute done; safe to overwrite

        // ---- write staged x (hi/lo, subtiled, nb-XOR on nl) ----
        #pragma unroll
        for (int it = 0; it < 8; ++it) {
            int f = it * 256 + t;
            int kk = f >> 5, f4 = f & 31;
            int nb = f4 >> 2;
            int kb = kk >> 2, kl = kk & 3;
            float4 v4 = xs[it];
            float vals[4] = {v4.x, v4.y, v4.z, v4.w};
            #pragma unroll
            for (int s4 = 0; s4 < 4; ++s4) {
                float val = vals[s4];
                int nl = ((f4 & 3) * 4 + s4) ^ nb;
                unsigned short h = f2bf(val);
                float hf = __uint_as_float(((unsigned)h) << 16);
                xh[nb][kb][nl][kl] = h;
                xl[nb][kb][nl][kl] = f2bf(val - hf);
            }
        }
        // ---- gather A-tile from strip (granule-XOR swizzled) ----
        #pragma unroll
        for (int it = 0; it < 4; ++it) {
            int f = it * 256 + t;
            int il = f >> 4, fq = f & 15;
            int kk0 = fq * 4;
            bf16x4 hv, lv;
            #pragma unroll
            for (int j = 0; j < 4; ++j) {
                int d = (i0 + il - (kt * 64 + kk0 + j)) & 1023;
                hv[j] = (short)strip_hi[d];
                lv[j] = (short)strip_lo[d];
            }
            int pos = (((fq >> 1) ^ (il & 7)) << 3) + ((fq & 1) << 2);
            *(bf16x4*)&A_hi[il][pos] = hv;
            *(bf16x4*)&A_lo[il][pos] = lv;
        }
        __syncthreads();

        // ---- prefetch next tile's globals (hide under MFMAs) ----
        if (kt < 15) {
            #pragma unroll
            for (int it = 0; it < 8; ++it) {
                int f = it * 256 + t;
                int kk = f >> 5, f4 = f & 31;
                int nl = f4 * 4;
                int kgl = (kt + 1) * 64 + kk;
                int cy = cy0 + (nl >> 6);
                int l = ((kgl & 127) << 3) | cy;
                int h2 = kgl >> 7;
                xs[it] = *(const float4*)(qb + l * 512 + h2 * 64 + (nl & 63));
            }
        }

        // ---- compute: 2 k-steps of 32 ----
        #pragma unroll
        for (int s = 0; s < 2; ++s) {
            bf16x8 Ah[2], Al[2];
            #pragma unroll
            for (int mf = 0; mf < 2; ++mf) {
                int row = wi * 32 + 16 * mf + m16;
                int pos = (((s * 4 + g) ^ (m16 & 7)) << 3);
                Ah[mf] = *(bf16x8*)&A_hi[row][pos];
                Al[mf] = *(bf16x8*)&A_lo[row][pos];
            }
            #pragma unroll
            for (int nf = 0; nf < 4; ++nf) {
                int nbr = wn * 4 + nf;
                int nlr = m16 ^ nbr;
                int kb0 = s * 8 + 2 * g;
                bf16x4 h0 = *(bf16x4*)&xh[nbr][kb0][nlr][0];
                bf16x4 h1 = *(bf16x4*)&xh[nbr][kb0 + 1][nlr][0];
                bf16x4 l0 = *(bf16x4*)&xl[nbr][kb0][nlr][0];
                bf16x4 l1 = *(bf16x4*)&xl[nbr][kb0 + 1][nlr][0];
                bf16x8 Bh, Bl;
                #pragma unroll
                for (int j = 0; j < 4; ++j) {
                    Bh[j] = h0[j]; Bh[4 + j] = h1[j];
                    Bl[j] = l0[j]; Bl[4 + j] = l1[j];
                }
                #pragma unroll
                for (int mf = 0; mf < 2; ++mf) {
                    acc[mf][nf] = __builtin_amdgcn_mfma_f32_16x16x32_bf16(Ah[mf], Bh, acc[mf][nf], 0, 0, 0);
                    acc[mf][nf] = __builtin_amdgcn_mfma_f32_16x16x32_bf16(Ah[mf], Bl, acc[mf][nf], 0, 0, 0);
                    acc[mf][nf] = __builtin_amdgcn_mfma_f32_16x16x32_bf16(Al[mf], Bh, acc[mf][nf], 0, 0, 0);
                }
            }
        }
    }

    // ---- epilogue: theta partials (re from q, sv/cv, reduce over 128 n) ----
    float svacc[2][4], cvacc[2][4];
    #pragma unroll
    for (int mf = 0; mf < 2; ++mf)
        #pragma unroll
        for (int r = 0; r < 4; ++r) { svacc[mf][r] = 0.f; cvacc[mf][r] = 0.f; }

    #pragma unroll
    for (int mf = 0; mf < 2; ++mf) {
        #pragma unroll
        for (int nf = 0; nf < 4; ++nf) {
            #pragma unroll
            for (int r = 0; r < 4; ++r) {
                float iv = acc[mf][nf][r];
                int ig = i0 + wi * 32 + 16 * mf + 4 * g + r;
                int ng = n0 + wn * 64 + 16 * nf + m16;
                int cc2 = ng & 511;
                int cy = cc2 >> 6, e = cc2 & 63;
                int l = ((ig & 127) << 3) | cy;
                int h2 = ig >> 7;
                float re = qb[l * 512 + h2 * 64 + e];
                float rr = sqrtf(re * re + iv * iv);
                float sv, cv;
                if (rr > 0.f) { sv = iv / rr; cv = re / rr; }
                else { sv = 0.f; cv = 1.f; }
                svacc[mf][r] += sv;
                cvacc[mf][r] += cv;
            }
        }
    }
    #pragma unroll
    for (int mf = 0; mf < 2; ++mf) {
        #pragma unroll
        for (int r = 0; r < 4; ++r) {
            float s = svacc[mf][r], c = cvacc[mf][r];
            s += __shfl_xor(s, 1); s += __shfl_xor(s, 2);
            s += __shfl_xor(s, 4); s += __shfl_xor(s, 8);
            c += __shfl_xor(c, 1); c += __shfl_xor(c, 2);
            c += __shfl_xor(c, 4); c += __shfl_xor(c, 8);
            if (m16 == 0) {
                psv[wv][16 * mf + 4 * g + r] = s;
                pcv[wv][16 * mf + 4 * g + r] = c;
            }
        }
    }
    __syncthreads();
    if (t < 64) {
        int wg = (t >> 5) * 2;
        float s = psv[wg][t & 31] + psv[wg + 1][t & 31];
        float c = pcv[wg][t & 31] + pcv[wg + 1][t & 31];
        size_t oidx = ((size_t)bq * 1024 + (i0 + t)) * 4 + quad;
        part_s[oidx] = s;
        part_c[oidx] = c;
    }
}

// ---------------- kernel 4: finalize theta ----------------
__global__ __launch_bounds__(256) void k_theta_fin(const float* __restrict__ part_s,
                                                   const float* __restrict__ part_c,
                                                   float* __restrict__ theta) {
    int tid = blockIdx.x * 256 + threadIdx.x;
    if (tid >= BB * LL) return;
    float ss = 0.f, cc = 0.f;
    #pragma unroll
    for (int qd = 0; qd < 4; ++qd) {
        ss += part_s[(size_t)tid * 4 + qd];
        cc += part_c[(size_t)tid * 4 + qd];
    }
    theta[tid] = atan2f(ss, cc);
}

// ---------------- kernel 5: MFMA flash attention (round-5, validated) ----------
__global__ __launch_bounds__(256) void k_attn(const float* __restrict__ q,
                                              const float* __restrict__ k,
                                              const float* __restrict__ v,
                                              const float* __restrict__ psi,
                                              const float* __restrict__ taut,
                                              const float* __restrict__ theta,
                                              float* __restrict__ out) {
    __shared__ unsigned short q_lds[64][64];
    __shared__ unsigned short k_lds[64][64];
    __shared__ unsigned short v_sub[4][16][16][4];
    __shared__ float psi_s[64], th_s[64];

    int t = threadIdx.x;
    int lid = t & 63;
    int wv = t >> 6;
    int m16 = lid & 15;
    int g = lid >> 4;

    int blk = blockIdx.x;
    int qt = blk & 15;
    int bh = blk >> 4;
    int h = bh & 7, b = bh >> 3;
    int l0 = qt * 64;

    const float* qg = q + ((size_t)(b * LL + l0) * CC + (size_t)h * EE);
    const float* kg = k + ((size_t)b * LL * CC + (size_t)h * EE);
    const float* vg = v + ((size_t)b * LL * CC + (size_t)h * EE);
    const float* psib = psi + (size_t)bh * LL;
    const float* thb = theta + (size_t)b * LL;

    int qrow = wv * 16 + m16;
    float psiq = psib[l0 + qrow];
    float thq  = thb[l0 + qrow];
    float ta   = taut[(size_t)bh * LL + l0 + qrow];
    float i2t  = 1.f / (2.f * ta * ta);

    #pragma unroll
    for (int it = 0; it < 2; ++it) {
        int flat = it * 256 + t;
        int row = flat >> 3, gr = flat & 7;
        const float* src = qg + (size_t)row * CC + gr * 8;
        float4 a4 = *(const float4*)src;
        float4 b4 = *(const float4*)(src + 4);
        int pos = gr ^ (row & 7);
        bf16x8 kv;
        kv[0] = (short)f2bf(0.125f * a4.x); kv[1] = (short)f2bf(0.125f * a4.y);
        kv[2] = (short)f2bf(0.125f * a4.z); kv[3] = (short)f2bf(0.125f * a4.w);
        kv[4] = (short)f2bf(0.125f * b4.x); kv[5] = (short)f2bf(0.125f * b4.y);
        kv[6] = (short)f2bf(0.125f * b4.z); kv[7] = (short)f2bf(0.125f * b4.w);
        *(bf16x8*)&q_lds[row][pos * 8] = kv;
    }
    __syncthreads();

    bf16x8 qf[2];
    #pragma unroll
    for (int ec = 0; ec < 2; ++ec) {
        int pos = (4 * ec + g) ^ (m16 & 7);
        qf[ec] = *(bf16x8*)&q_lds[wv * 16 + m16][pos * 8];
    }

    f32x4 accS[4], accP[4];
    #pragma unroll
    for (int f = 0; f < 4; ++f) {
        accS[f] = (f32x4){0.f, 0.f, 0.f, 0.f};
        accP[f] = (f32x4){0.f, 0.f, 0.f, 0.f};
    }
    float mrun = -INFINITY, ssel = 0.f, sprl = 0.f, spgl = 0.f;

    for (int tile = 0; tile < 16; ++tile) {
        if (tile) __syncthreads();
        int s0g = tile * 64;

        #pragma unroll
        for (int it = 0; it < 2; ++it) {
            int flat = it * 256 + t;
            int row = flat >> 3, gr = flat & 7;
            const float* src = kg + (size_t)(s0g + row) * CC + gr * 8;
            float4 a4 = *(const float4*)src;
            float4 b4 = *(const float4*)(src + 4);
            int pos = gr ^ (row & 7);
            bf16x8 kv;
        kv[0] = (short)f2bf(a4.x); kv[1] = (short)f2bf(a4.y);
        kv[2] = (short)f2bf(a4.z); kv[3] = (short)f2bf(a4.w);
        kv[4] = (short)f2bf(b4.x); kv[5] = (short)f2bf(b4.y);
        kv[6] = (short)f2bf(b4.z); kv[7] = (short)f2bf(b4.w);
            *(bf16x8*)&k_lds[row][pos * 8] = kv;
        }
        #pragma unroll
        for (int it = 0; it < 4; ++it) {
            int flat = it * 256 + t;
            int s = flat >> 4, i = flat & 15;
            float4 a4 = *(const float4*)(vg + (size_t)(s0g + s) * CC + i * 4);
            int eb = i >> 2, e4 = (i & 3) * 4, sg = s >> 2, sl = s & 3;
            v_sub[eb][sg][e4 + 0][sl] = f2bf(a4.x);
            v_sub[eb][sg][e4 + 1][sl] = f2bf(a4.y);
            v_sub[eb][sg][e4 + 2][sl] = f2bf(a4.z);
            v_sub[eb][sg][e4 + 3][sl] = f2bf(a4.w);
        }
        if (t < 64) { psi_s[t] = psib[s0g + t]; th_s[t] = thb[s0g + t]; }
        __syncthreads();

        f32x4 st[4];
        #pragma unroll
        for (int f = 0; f < 4; ++f) st[f] = (f32x4){0.f, 0.f, 0.f, 0.f};
        #pragma unroll
        for (int ec = 0; ec < 2; ++ec) {
            int pos = (4 * ec + g) ^ (m16 & 7);
            #pragma unroll
            for (int f = 0; f < 4; ++f) {
                bf16x8 ka = *(bf16x8*)&k_lds[16 * f + m16][pos * 8];
                st[f] = __builtin_amdgcn_mfma_f32_16x16x32_bf16(ka, qf[ec], st[f], 0, 0, 0);
            }
        }

        float mx = st[0][0];
        #pragma unroll
        for (int f = 0; f < 4; ++f)
            #pragma unroll
            for (int r = 0; r < 4; ++r) mx = fmaxf(mx, st[f][r]);
        mx = fmaxf(mx, __shfl_xor(mx, 16));
        mx = fmaxf(mx, __shfl_xor(mx, 32));
        float mnew = fmaxf(mrun, mx);
        float scl = __expf(mrun - mnew);
        mrun = mnew;

        float psum = 0.f;
        unsigned short pb[16], gb[16];
        #pragma unroll
        for (int f = 0; f < 4; ++f) {
            float4 ps4 = *(const float4*)&psi_s[16 * f + 4 * g];
            float4 th4 = *(const float4*)&th_s[16 * f + 4 * g];
            float pss[4] = {ps4.x, ps4.y, ps4.z, ps4.w};
            float ths[4] = {th4.x, th4.y, th4.z, th4.w};
            #pragma unroll
            for (int r = 0; r < 4; ++r) {
                float p = __expf(st[f][r] - mnew);
                psum += p;
                float d = psiq - pss[r];
                float pr = __expf(-0.5f * d * d);
                float dp = __sinf(0.5f * (thq - ths[r]));
                float gg = __expf(-dp * dp * i2t);
                float pgv = pr * gg;
                sprl += pr; spgl += pgv;
                pb[f * 4 + r] = f2bf(p);
                gb[f * 4 + r] = f2bf(pgv);
            }
        }
        ssel = ssel * scl + psum;

        float sr[4];
        #pragma unroll
        for (int r = 0; r < 4; ++r) sr[r] = __shfl(scl, 4 * g + r);
        #pragma unroll
        for (int f = 0; f < 4; ++f)
            #pragma unroll
            for (int r = 0; r < 4; ++r) accS[f][r] *= sr[r];

        bf16x8 pS[2], pG[2];
        #pragma unroll
        for (int c = 0; c < 2; ++c)
            #pragma unroll
            for (int j = 0; j < 8; ++j) {
                pS[c][j] = (short)pb[c * 8 + j];
                pG[c][j] = (short)gb[c * 8 + j];
            }

        #pragma unroll
        for (int c = 0; c < 2; ++c) {
            #pragma unroll
            for (int ef = 0; ef < 4; ++ef) {
                bf16x4 v0 = *(bf16x4*)&v_sub[ef][8 * c + g][m16][0];
                bf16x4 v1 = *(bf16x4*)&v_sub[ef][8 * c + 4 + g][m16][0];
                bf16x8 vb;
                vb[0] = v0[0]; vb[1] = v0[1]; vb[2] = v0[2]; vb[3] = v0[3];
                vb[4] = v1[0]; vb[5] = v1[1]; vb[6] = v1[2]; vb[7] = v1[3];
                accS[ef] = __builtin_amdgcn_mfma_f32_16x16x32_bf16(pS[c], vb, accS[ef], 0, 0, 0);
                accP[ef] = __builtin_amdgcn_mfma_f32_16x16x32_bf16(pG[c], vb, accP[ef], 0, 0, 0);
            }
        }
    }

    ssel += __shfl_xor(ssel, 16); ssel += __shfl_xor(ssel, 32);
    sprl += __shfl_xor(sprl, 16); sprl += __shfl_xor(sprl, 32);
    spgl += __shfl_xor(spgl, 16); spgl += __shfl_xor(spgl, 32);
    float cs = 0.9f / ssel;
    float cp = 0.1f / (spgl + 1e-6f * (sprl + 1e-6f));
    float* ob = out + ((size_t)(b * LL + l0 + wv * 16) * CC + (size_t)h * EE);
    #pragma unroll
    for (int r = 0; r < 4; ++r) {
        float csr = __shfl(cs, 4 * g + r);
        float cpr = __shfl(cp, 4 * g + r);
        #pragma unroll
        for (int f = 0; f < 4; ++f) {
            ob[(size_t)(4 * g + r) * CC + 16 * f + m16] =
                csr * accS[f][r] + cpr * accP[f][r];
        }
    }
}

extern "C" void kernel_launch(void* const* d_in, const int* in_sizes, int n_in,
                              void* d_out, int out_size, void* d_ws, size_t ws_size,
                              hipStream_t stream) {
    const float* q = (const float*)d_in[0];
    const float* k = (const float*)d_in[1];
    const float* v = (const float*)d_in[2];
    // d_in[3] = sigma (unused by the reference)
    const float* hurst = (const float*)d_in[4];
    const float* tau = (const float*)d_in[5];
    float* out = (float*)d_out;

    float* ws = (float*)d_ws;
    float* gi     = ws;                            // 1024
    float* psi    = gi + LL;                       // 32768
    float* taut   = psi + (size_t)BB * HH * LL;    // 32768
    float* theta  = taut + (size_t)BB * HH * LL;   // 4096
    float* part_s = theta + (size_t)BB * LL;       // 16384
    float* part_c = part_s + (size_t)BB * LL * 4;  // 16384

    k_gi<<<1, LL, 0, stream>>>(gi);
    k_scan<<<BB * HH, LL, 0, stream>>>(hurst, tau, psi, taut);
    k_hilb<<<256, 256, 0, stream>>>(q, gi, part_s, part_c);
    k_theta_fin<<<(BB * LL) / 256, 256, 0, stream>>>(part_s, part_c, theta);
    k_attn<<<BB * HH * (LL / 64), 256, 0, stream>>>(q, k, v, psi, taut, theta, out);
}

// Round 7
// 108.297 us; speedup vs baseline: 31.2491x; 1.1806x over previous
//
#include <hip/hip_runtime.h>
#include <math.h>

#define LL 1024
#define BB 4
#define HH 8
#define EE 64
#define CC (HH*EE)  // 512

typedef __attribute__((ext_vector_type(4))) float f32x4;
typedef __attribute__((ext_vector_type(8))) short bf16x8;
typedef __attribute__((ext_vector_type(4))) short bf16x4;

__device__ __forceinline__ unsigned short f2bf(float x) {
    unsigned u = __float_as_uint(x);
    u += 0x7FFFu + ((u >> 16) & 1u);   // round-to-nearest-even
    return (unsigned short)(u >> 16);
}

// global_load_lds 16B: per-lane global src, wave-uniform LDS dest (+lane*16 by HW)
__device__ __forceinline__ void dma16(const void* g, void* l) {
    typedef const __attribute__((address_space(1))) unsigned int* gup;
    typedef __attribute__((address_space(3))) unsigned int* lup;
    gup gp = (gup)(unsigned long long)g;
    lup lp = (lup)(unsigned int)(unsigned long long)l;
    __builtin_amdgcn_global_load_lds(gp, lp, 16, 0, 0);
}

// ---------------- kernel 1: Hilbert circular-conv kernel table ----------------
__global__ void k_gi(float* gi) {
    int d = blockIdx.x * blockDim.x + threadIdx.x;
    if (d >= LL) return;
    float v = 0.f;
    if (d & 1) {
        float a = 3.14159265358979323846f * (float)d / (float)LL;
        v = (2.0f / (float)LL) * (cosf(a) / sinf(a));
    }
    gi[d] = v;
}

// ---------------- kernel 2: hurst->psi cumsum, tau_t ----------------
__global__ __launch_bounds__(1024) void k_scan(const float* __restrict__ hurst,
                                               const float* __restrict__ tau,
                                               float* __restrict__ psi,
                                               float* __restrict__ taut) {
    __shared__ float s[LL];
    int bh = blockIdx.x;
    int b = bh / HH, h = bh % HH;
    int l = threadIdx.x;
    float hu = hurst[((size_t)b * LL + l) * HH + h];
    float ht = 1.f / (1.f + expf(-hu)) * 0.99f + 0.01f;
    s[l] = expf(2.0f * ht);
    __syncthreads();
    for (int off = 1; off < LL; off <<= 1) {
        float t = (l >= off) ? s[l - off] : 0.f;
        __syncthreads();
        s[l] += t;
        __syncthreads();
    }
    psi[((size_t)b * HH + h) * LL + l] = s[l];
    float tv = tau[((size_t)b * LL + l) * HH + h];
    taut[((size_t)b * HH + h) * LL + l] = 1.f / (1.f + expf(-tv)) * 0.9f + 0.1f;
}

// ---------------- kernel 3: MFMA Hilbert conv (split bf16 GEMM) + theta partials
// (validated round 6, unchanged)
__global__ __launch_bounds__(256) void k_hilb(const float* __restrict__ q,
                                              const float* __restrict__ gi,
                                              float* __restrict__ part_s,
                                              float* __restrict__ part_c) {
    __shared__ unsigned short strip_hi[1024], strip_lo[1024];
    __shared__ unsigned short A_hi[64][64], A_lo[64][64];
    __shared__ unsigned short xh[8][16][16][4], xl[8][16][16][4];
    __shared__ float psv[4][32], pcv[4][32];

    int t = threadIdx.x;
    int lid = t & 63;
    int wv = t >> 6;
    int m16 = lid & 15;
    int g = lid >> 4;
    int wi = wv >> 1, wn = wv & 1;

    int bid = blockIdx.x;
    int xcd = bid & 7, o = bid >> 3;
    int im = ((xcd >> 2) << 3) + (o & 7);
    int in = ((xcd & 3) << 2) + (o >> 3);
    int i0 = im * 64, n0 = in * 128;
    int bq = n0 >> 9;
    int cy0 = (n0 & 511) >> 6;
    int quad = in & 3;

    const float* qb = q + (size_t)bq * LL * CC;

    float4 xs[8];
    {
        #pragma unroll
        for (int it = 0; it < 8; ++it) {
            int f = it * 256 + t;
            int kk = f >> 5, f4 = f & 31;
            int nl = f4 * 4;
            int kgl = kk;
            int cy = cy0 + (nl >> 6);
            int l = ((kgl & 127) << 3) | cy;
            int h2 = kgl >> 7;
            xs[it] = *(const float4*)(qb + l * 512 + h2 * 64 + (nl & 63));
        }
    }
    for (int x = t; x < 1024; x += 256) {
        float gg = gi[x];
        unsigned short h = f2bf(gg);
        float hf = __uint_as_float(((unsigned)h) << 16);
        strip_hi[x] = h;
        strip_lo[x] = f2bf(gg - hf);
    }
    __syncthreads();

    f32x4 acc[2][4];
    #pragma unroll
    for (int mf = 0; mf < 2; ++mf)
        #pragma unroll
        for (int nf = 0; nf < 4; ++nf) acc[mf][nf] = (f32x4){0.f, 0.f, 0.f, 0.f};

    for (int kt = 0; kt < 16; ++kt) {
        if (kt) __syncthreads();

        #pragma unroll
        for (int it = 0; it < 8; ++it) {
            int f = it * 256 + t;
            int kk = f >> 5, f4 = f & 31;
            int nb = f4 >> 2;
            int kb = kk >> 2, kl = kk & 3;
            float4 v4 = xs[it];
            float vals[4] = {v4.x, v4.y, v4.z, v4.w};
            #pragma unroll
            for (int s4 = 0; s4 < 4; ++s4) {
                float val = vals[s4];
                int nl = ((f4 & 3) * 4 + s4) ^ nb;
                unsigned short h = f2bf(val);
                float hf = __uint_as_float(((unsigned)h) << 16);
                xh[nb][kb][nl][kl] = h;
                xl[nb][kb][nl][kl] = f2bf(val - hf);
            }
        }
        #pragma unroll
        for (int it = 0; it < 4; ++it) {
            int f = it * 256 + t;
            int il = f >> 4, fq = f & 15;
            int kk0 = fq * 4;
            bf16x4 hv, lv;
            #pragma unroll
            for (int j = 0; j < 4; ++j) {
                int d = (i0 + il - (kt * 64 + kk0 + j)) & 1023;
                hv[j] = (short)strip_hi[d];
                lv[j] = (short)strip_lo[d];
            }
            int pos = (((fq >> 1) ^ (il & 7)) << 3) + ((fq & 1) << 2);
            *(bf16x4*)&A_hi[il][pos] = hv;
            *(bf16x4*)&A_lo[il][pos] = lv;
        }
        __syncthreads();

        if (kt < 15) {
            #pragma unroll
            for (int it = 0; it < 8; ++it) {
                int f = it * 256 + t;
                int kk = f >> 5, f4 = f & 31;
                int nl = f4 * 4;
                int kgl = (kt + 1) * 64 + kk;
                int cy = cy0 + (nl >> 6);
                int l = ((kgl & 127) << 3) | cy;
                int h2 = kgl >> 7;
                xs[it] = *(const float4*)(qb + l * 512 + h2 * 64 + (nl & 63));
            }
        }

        #pragma unroll
        for (int s = 0; s < 2; ++s) {
            bf16x8 Ah[2], Al[2];
            #pragma unroll
            for (int mf = 0; mf < 2; ++mf) {
                int row = wi * 32 + 16 * mf + m16;
                int pos = (((s * 4 + g) ^ (m16 & 7)) << 3);
                Ah[mf] = *(bf16x8*)&A_hi[row][pos];
                Al[mf] = *(bf16x8*)&A_lo[row][pos];
            }
            #pragma unroll
            for (int nf = 0; nf < 4; ++nf) {
                int nbr = wn * 4 + nf;
                int nlr = m16 ^ nbr;
                int kb0 = s * 8 + 2 * g;
                bf16x4 h0 = *(bf16x4*)&xh[nbr][kb0][nlr][0];
                bf16x4 h1 = *(bf16x4*)&xh[nbr][kb0 + 1][nlr][0];
                bf16x4 l0 = *(bf16x4*)&xl[nbr][kb0][nlr][0];
                bf16x4 l1 = *(bf16x4*)&xl[nbr][kb0 + 1][nlr][0];
                bf16x8 Bh, Bl;
                #pragma unroll
                for (int j = 0; j < 4; ++j) {
                    Bh[j] = h0[j]; Bh[4 + j] = h1[j];
                    Bl[j] = l0[j]; Bl[4 + j] = l1[j];
                }
                #pragma unroll
                for (int mf = 0; mf < 2; ++mf) {
                    acc[mf][nf] = __builtin_amdgcn_mfma_f32_16x16x32_bf16(Ah[mf], Bh, acc[mf][nf], 0, 0, 0);
                    acc[mf][nf] = __builtin_amdgcn_mfma_f32_16x16x32_bf16(Ah[mf], Bl, acc[mf][nf], 0, 0, 0);
                    acc[mf][nf] = __builtin_amdgcn_mfma_f32_16x16x32_bf16(Al[mf], Bh, acc[mf][nf], 0, 0, 0);
                }
            }
        }
    }

    float svacc[2][4], cvacc[2][4];
    #pragma unroll
    for (int mf = 0; mf < 2; ++mf)
        #pragma unroll
        for (int r = 0; r < 4; ++r) { svacc[mf][r] = 0.f; cvacc[mf][r] = 0.f; }

    #pragma unroll
    for (int mf = 0; mf < 2; ++mf) {
        #pragma unroll
        for (int nf = 0; nf < 4; ++nf) {
            #pragma unroll
            for (int r = 0; r < 4; ++r) {
                float iv = acc[mf][nf][r];
                int ig = i0 + wi * 32 + 16 * mf + 4 * g + r;
                int ng = n0 + wn * 64 + 16 * nf + m16;
                int cc2 = ng & 511;
                int cy = cc2 >> 6, e = cc2 & 63;
                int l = ((ig & 127) << 3) | cy;
                int h2 = ig >> 7;
                float re = qb[l * 512 + h2 * 64 + e];
                float rr = sqrtf(re * re + iv * iv);
                float sv, cv;
                if (rr > 0.f) { sv = iv / rr; cv = re / rr; }
                else { sv = 0.f; cv = 1.f; }
                svacc[mf][r] += sv;
                cvacc[mf][r] += cv;
            }
        }
    }
    #pragma unroll
    for (int mf = 0; mf < 2; ++mf) {
        #pragma unroll
        for (int r = 0; r < 4; ++r) {
            float s = svacc[mf][r], c = cvacc[mf][r];
            s += __shfl_xor(s, 1); s += __shfl_xor(s, 2);
            s += __shfl_xor(s, 4); s += __shfl_xor(s, 8);
            c += __shfl_xor(c, 1); c += __shfl_xor(c, 2);
            c += __shfl_xor(c, 4); c += __shfl_xor(c, 8);
            if (m16 == 0) {
                psv[wv][16 * mf + 4 * g + r] = s;
                pcv[wv][16 * mf + 4 * g + r] = c;
            }
        }
    }
    __syncthreads();
    if (t < 64) {
        int wg = (t >> 5) * 2;
        float s = psv[wg][t & 31] + psv[wg + 1][t & 31];
        float c = pcv[wg][t & 31] + pcv[wg + 1][t & 31];
        size_t oidx = ((size_t)bq * 1024 + (i0 + t)) * 4 + quad;
        part_s[oidx] = s;
        part_c[oidx] = c;
    }
}

// ---------------- kernel 4: finalize theta -> cos/sin ----------------
__global__ __launch_bounds__(256) void k_theta_fin(const float* __restrict__ part_s,
                                                   const float* __restrict__ part_c,
                                                   float* __restrict__ costh,
                                                   float* __restrict__ sinth) {
    int tid = blockIdx.x * 256 + threadIdx.x;
    if (tid >= BB * LL) return;
    float ss = 0.f, cc = 0.f;
    #pragma unroll
    for (int qd = 0; qd < 4; ++qd) {
        ss += part_s[(size_t)tid * 4 + qd];
        cc += part_c[(size_t)tid * 4 + qd];
    }
    float r2 = ss * ss + cc * cc;
    if (r2 > 0.f) {
        float rn = rsqrtf(r2);
        costh[tid] = cc * rn;
        sinth[tid] = ss * rn;
    } else {
        costh[tid] = 1.f;
        sinth[tid] = 0.f;
    }
}

// ---------------- kernel 5: prep — bf16 pre-swizzled Q/K, frag-layout V, pcs ----
// grid: B*H*16 blocks (one 64-row tile each), 256 threads.
__global__ __launch_bounds__(256) void k_prep(const float* __restrict__ q,
                                              const float* __restrict__ k,
                                              const float* __restrict__ v,
                                              const float* __restrict__ psi,
                                              const float* __restrict__ taut,
                                              const float* __restrict__ costh,
                                              const float* __restrict__ sinth,
                                              unsigned short* __restrict__ Qp,
                                              unsigned short* __restrict__ Kp,
                                              unsigned short* __restrict__ Vp,
                                              float* __restrict__ pcs) {
    __shared__ unsigned short vt[4096];
    int t = threadIdx.x;
    int blk = blockIdx.x;
    int tile = blk & 15;
    int bh = blk >> 4;
    int h = bh & 7, b = bh >> 3;
    int l0 = tile * 64;

    const float* qg = q + ((size_t)(b * LL + l0) * CC + (size_t)h * EE);
    const float* kg = k + ((size_t)(b * LL + l0) * CC + (size_t)h * EE);
    const float* vg = v + ((size_t)(b * LL + l0) * CC + (size_t)h * EE);
    unsigned short* Qo = Qp + ((size_t)bh * LL + l0) * 64;
    unsigned short* Ko = Kp + ((size_t)bh * LL + l0) * 64;
    unsigned short* Vo = Vp + ((size_t)bh * 16 + tile) * 4096;

    // Q (x0.125) and K: row-major bf16 with granule-XOR pre-swizzle
    #pragma unroll
    for (int it = 0; it < 2; ++it) {
        int x = it * 256 + t;          // 512 granules
        int row = x >> 3, gr = x & 7;
        int pos = (gr ^ (row & 7)) * 8;
        const float* src = qg + (size_t)row * CC + gr * 8;
        float4 a4 = *(const float4*)src;
        float4 b4 = *(const float4*)(src + 4);
        bf16x8 o;
        o[0] = (short)f2bf(0.125f * a4.x); o[1] = (short)f2bf(0.125f * a4.y);
        o[2] = (short)f2bf(0.125f * a4.z); o[3] = (short)f2bf(0.125f * a4.w);
        o[4] = (short)f2bf(0.125f * b4.x); o[5] = (short)f2bf(0.125f * b4.y);
        o[6] = (short)f2bf(0.125f * b4.z); o[7] = (short)f2bf(0.125f * b4.w);
        *(bf16x8*)&Qo[row * 64 + pos] = o;
        src = kg + (size_t)row * CC + gr * 8;
        a4 = *(const float4*)src;
        b4 = *(const float4*)(src + 4);
        o[0] = (short)f2bf(a4.x); o[1] = (short)f2bf(a4.y);
        o[2] = (short)f2bf(a4.z); o[3] = (short)f2bf(a4.w);
        o[4] = (short)f2bf(b4.x); o[5] = (short)f2bf(b4.y);
        o[6] = (short)f2bf(b4.z); o[7] = (short)f2bf(b4.w);
        *(bf16x8*)&Ko[row * 64 + pos] = o;
    }

    // V: PV B-frag layout (ef,c,g4,m16,jj): s = 32c+16(jj>>2)+4g4+(jj&3), e = 16ef+m16
    #pragma unroll
    for (int it = 0; it < 4; ++it) {
        int x = it * 256 + t;          // 1024 float4s
        int s = x >> 4, i = x & 15;
        float4 a4 = *(const float4*)(vg + (size_t)s * CC + i * 4);
        int c = s >> 5, g4 = (s >> 2) & 3;
        int jj = ((s >> 4) & 1) * 4 + (s & 3);
        float vals[4] = {a4.x, a4.y, a4.z, a4.w};
        #pragma unroll
        for (int j2 = 0; j2 < 4; ++j2) {
            int e = i * 4 + j2;
            int ef = e >> 4, m16 = e & 15;
            vt[((((ef * 2 + c) * 4 + g4) * 16 + m16) * 8) + jj] = f2bf(vals[j2]);
        }
    }
    __syncthreads();
    #pragma unroll
    for (int it = 0; it < 2; ++it) {
        int x = it * 256 + t;
        *(bf16x8*)&Vo[x * 8] = *(bf16x8*)&vt[x * 8];
    }

    // pcs[bh][l] = (psi, cos, sin, 1/(2 tau^2))
    if (t < 64) {
        int l = l0 + t;
        float ta = taut[(size_t)bh * LL + l];
        float4 o;
        o.x = psi[(size_t)bh * LL + l];
        o.y = costh[(size_t)b * LL + l];
        o.z = sinth[(size_t)b * LL + l];
        o.w = 1.f / (2.f * ta * ta);
        *(float4*)&pcs[((size_t)bh * LL + l) * 4] = o;
    }
}

// ---------------- kernel 6: MFMA flash attention, DMA-staged, 2-phase ----------
__global__ __launch_bounds__(256) void k_attn(const unsigned short* __restrict__ Qp,
                                              const unsigned short* __restrict__ Kp,
                                              const unsigned short* __restrict__ Vp,
                                              const float* __restrict__ pcs,
                                              float* __restrict__ out) {
    __shared__ unsigned short q_lds[4096];
    __shared__ unsigned short k_lds[2][4096];
    __shared__ unsigned short v_lds[2][4096];
    __shared__ float pcs_lds[2][256];

    int t = threadIdx.x;
    int lid = t & 63;
    int wv = t >> 6;
    int m16 = lid & 15;
    int g = lid >> 4;

    // XCD swizzle: 16 q-blocks of one (b,h) land on one XCD (512 = 8*64)
    int bid = blockIdx.x;
    int blk = (bid & 7) * 64 + (bid >> 3);
    int qt = blk & 15;
    int bh = blk >> 4;
    int h = bh & 7, b = bh >> 3;
    int l0 = qt * 64;

    const unsigned short* Qg = Qp + ((size_t)bh * LL + l0) * 64;
    const unsigned short* Kg = Kp + (size_t)bh * LL * 64;
    const unsigned short* Vg = Vp + (size_t)bh * LL * 64;
    const float* pcsg = pcs + (size_t)bh * LL * 4;

    int qrow = wv * 16 + m16;
    float4 myq = *(const float4*)&pcsg[(size_t)(l0 + qrow) * 4];
    float psiq = myq.x, cq = myq.y, sq = myq.z;
    float c1 = 0.5f * myq.w;    // gate arg = c1*cosD - c1

    // ---- prologue: DMA Q + tile 0 ----
    {
        const char* qb8 = (const char*)Qg;
        #pragma unroll
        for (int c = 0; c < 2; ++c) {
            int ch = wv + c * 4;
            dma16(qb8 + ch * 1024 + lid * 16, (char*)q_lds + ch * 1024);
        }
        const char* kb8 = (const char*)Kg;
        const char* vb8 = (const char*)Vg;
        #pragma unroll
        for (int c = 0; c < 2; ++c) {
            int ch = wv + c * 4;
            dma16(kb8 + ch * 1024 + lid * 16, (char*)k_lds[0] + ch * 1024);
            dma16(vb8 + ch * 1024 + lid * 16, (char*)v_lds[0] + ch * 1024);
        }
        if (wv == 0) dma16((const char*)pcsg + lid * 16, (char*)pcs_lds[0]);
    }
    __syncthreads();

    // persistent Q B-frags
    bf16x8 qf[2];
    #pragma unroll
    for (int ec = 0; ec < 2; ++ec) {
        int pos = (4 * ec + g) ^ (m16 & 7);
        qf[ec] = *(bf16x8*)&q_lds[(wv * 16 + m16) * 64 + pos * 8];
    }

    f32x4 accS[4], accP[4];
    #pragma unroll
    for (int f = 0; f < 4; ++f) {
        accS[f] = (f32x4){0.f, 0.f, 0.f, 0.f};
        accP[f] = (f32x4){0.f, 0.f, 0.f, 0.f};
    }
    float mrun = -INFINITY, ssel = 0.f, sprl = 0.f, spgl = 0.f;
    int cur = 0;

    for (int tile = 0; tile < 16; ++tile) {
        // ---- stage next tile (overlaps compute; drained at this tile's barrier) ----
        if (tile < 15) {
            const char* kb8 = (const char*)Kg + (tile + 1) * 8192;
            const char* vb8 = (const char*)Vg + (tile + 1) * 8192;
            int nb = cur ^ 1;
            #pragma unroll
            for (int c = 0; c < 2; ++c) {
                int ch = wv + c * 4;
                dma16(kb8 + ch * 1024 + lid * 16, (char*)k_lds[nb] + ch * 1024);
                dma16(vb8 + ch * 1024 + lid * 16, (char*)v_lds[nb] + ch * 1024);
            }
            if (wv == 0) dma16((const char*)pcsg + (tile + 1) * 1024 + lid * 16,
                               (char*)pcs_lds[nb]);
        }

        // ---- S^T = mfma(K, Q) ----
        f32x4 st[4];
        #pragma unroll
        for (int f = 0; f < 4; ++f) st[f] = (f32x4){0.f, 0.f, 0.f, 0.f};
        #pragma unroll
        for (int ec = 0; ec < 2; ++ec) {
            int pos = (4 * ec + g) ^ (m16 & 7);
            #pragma unroll
            for (int f = 0; f < 4; ++f) {
                bf16x8 ka = *(bf16x8*)&k_lds[cur][(16 * f + m16) * 64 + pos * 8];
                st[f] = __builtin_amdgcn_mfma_f32_16x16x32_bf16(ka, qf[ec], st[f], 0, 0, 0);
            }
        }

        // ---- online softmax + prior/gate ----
        float mx = st[0][0];
        #pragma unroll
        for (int f = 0; f < 4; ++f)
            #pragma unroll
            for (int r = 0; r < 4; ++r) mx = fmaxf(mx, st[f][r]);
        mx = fmaxf(mx, __shfl_xor(mx, 16));
        mx = fmaxf(mx, __shfl_xor(mx, 32));
        float mnew = fmaxf(mrun, mx);
        float scl = __expf(mrun - mnew);
        mrun = mnew;

        float psum = 0.f;
        unsigned short pb[16], gb[16];
        #pragma unroll
        for (int f = 0; f < 4; ++f) {
            #pragma unroll
            for (int r = 0; r < 4; ++r) {
                float4 pc4 = *(const float4*)&pcs_lds[cur][(16 * f + 4 * g + r) * 4];
                float p = __expf(st[f][r] - mnew);
                psum += p;
                float d = psiq - pc4.x;
                float pr = __expf(-0.5f * d * d);
                float cd = cq * pc4.y + sq * pc4.z;
                float pg = pr * __expf(c1 * cd - c1);
                sprl += pr; spgl += pg;
                pb[f * 4 + r] = f2bf(p);
                gb[f * 4 + r] = f2bf(pg);
            }
        }
        ssel = ssel * scl + psum;

        float sr[4];
        #pragma unroll
        for (int r = 0; r < 4; ++r) sr[r] = __shfl(scl, 4 * g + r);
        #pragma unroll
        for (int f = 0; f < 4; ++f)
            #pragma unroll
            for (int r = 0; r < 4; ++r) accS[f][r] *= sr[r];

        bf16x8 pS[2], pG[2];
        #pragma unroll
        for (int c = 0; c < 2; ++c)
            #pragma unroll
            for (int j = 0; j < 8; ++j) {
                pS[c][j] = (short)pb[c * 8 + j];
                pG[c][j] = (short)gb[c * 8 + j];
            }

        // ---- PV: V B-frags are linear b128 reads ----
        #pragma unroll
        for (int c = 0; c < 2; ++c) {
            #pragma unroll
            for (int ef = 0; ef < 4; ++ef) {
                bf16x8 vb = *(bf16x8*)&v_lds[cur][(((ef * 2 + c) * 4 + g) * 16 + m16) * 8];
                accS[ef] = __builtin_amdgcn_mfma_f32_16x16x32_bf16(pS[c], vb, accS[ef], 0, 0, 0);
                accP[ef] = __builtin_amdgcn_mfma_f32_16x16x32_bf16(pG[c], vb, accP[ef], 0, 0, 0);
            }
        }

        __syncthreads();   // drains this wave's DMA (vmcnt 0) + barrier
        cur ^= 1;
    }

    // ---- epilogue ----
    ssel += __shfl_xor(ssel, 16); ssel += __shfl_xor(ssel, 32);
    sprl += __shfl_xor(sprl, 16); sprl += __shfl_xor(sprl, 32);
    spgl += __shfl_xor(spgl, 16); spgl += __shfl_xor(spgl, 32);
    float cs = 0.9f / ssel;
    float cp = 0.1f / (spgl + 1e-6f * (sprl + 1e-6f));
    float* ob = out + ((size_t)(b * LL + l0 + wv * 16) * CC + (size_t)h * EE);
    #pragma unroll
    for (int r = 0; r < 4; ++r) {
        float csr = __shfl(cs, 4 * g + r);
        float cpr = __shfl(cp, 4 * g + r);
        #pragma unroll
        for (int f = 0; f < 4; ++f) {
            ob[(size_t)(4 * g + r) * CC + 16 * f + m16] =
                csr * accS[f][r] + cpr * accP[f][r];
        }
    }
}

extern "C" void kernel_launch(void* const* d_in, const int* in_sizes, int n_in,
                              void* d_out, int out_size, void* d_ws, size_t ws_size,
                              hipStream_t stream) {
    const float* q = (const float*)d_in[0];
    const float* k = (const float*)d_in[1];
    const float* v = (const float*)d_in[2];
    // d_in[3] = sigma (unused by the reference)
    const float* hurst = (const float*)d_in[4];
    const float* tau = (const float*)d_in[5];
    float* out = (float*)d_out;

    float* ws = (float*)d_ws;
    float* gi     = ws;                            // 1024
    float* psi    = gi + LL;                       // 32768
    float* taut   = psi + (size_t)BB * HH * LL;    // 32768
    float* costh  = taut + (size_t)BB * HH * LL;   // 4096
    float* sinth  = costh + (size_t)BB * LL;       // 4096
    float* part_s = sinth + (size_t)BB * LL;       // 16384
    float* part_c = part_s + (size_t)BB * LL * 4;  // 16384
    float* pcs    = part_c + (size_t)BB * LL * 4;  // 131072
    unsigned short* Qp = (unsigned short*)(pcs + (size_t)BB * HH * LL * 4);
    unsigned short* Kp = Qp + (size_t)BB * HH * LL * 64;   // 2M ushorts each
    unsigned short* Vp = Kp + (size_t)BB * HH * LL * 64;

    k_gi<<<1, LL, 0, stream>>>(gi);
    k_scan<<<BB * HH, LL, 0, stream>>>(hurst, tau, psi, taut);
    k_hilb<<<256, 256, 0, stream>>>(q, gi, part_s, part_c);
    k_theta_fin<<<(BB * LL) / 256, 256, 0, stream>>>(part_s, part_c, costh, sinth);
    k_prep<<<BB * HH * 16, 256, 0, stream>>>(q, k, v, psi, taut, costh, sinth,
                                             Qp, Kp, Vp, pcs);
    k_attn<<<BB * HH * (LL / 64), 256, 0, stream>>>(Qp, Kp, Vp, pcs, out);
}